// Round 7
// baseline (400.037 us; speedup 1.0000x reference)
//
#include <hip/hip_runtime.h>
#include <hip/hip_bf16.h>
#include <math.h>

#define NNODES 100000
#define NEDGES 20000
#define NNZ_   2000000
#define FDIM   128
#define BN_EPS 1e-5f

// ---- bucket-sort geometry ----
#define NBUCK 256
#define CAP   9216        // per-bucket capacity (mean ~7812, sigma ~88 -> +16 sigma)
#define BPB_E 79          // edges/bucket (edge dir); bins/bucket = 79*8 = 632
#define BPB_N 391         // bins/bucket, node dir
#define SH_E  17          // edge entry = (e<<17)|n
#define SH_N  15          // node entry = (n<<15)|e
#define NPART 8           // node-table slices (one per XCD)
#define PSLICE 12500      // rows per slice -> 3.2 MB < 4 MiB XCD L2

typedef __attribute__((ext_vector_type(8))) short bf16x8_t;
typedef __attribute__((ext_vector_type(4))) float f32x4_t;
typedef __attribute__((ext_vector_type(8))) unsigned short u16x8_t;

__device__ __forceinline__ float sigmoidf_(float x) {
    return 1.0f / (1.0f + __expf(-x));
}
__device__ __forceinline__ float bf2f(unsigned short u) {
    return __uint_as_float(((unsigned)u) << 16);
}
__device__ __forceinline__ unsigned short f2bf(float f) {
    __hip_bfloat16 h = __float2bfloat16(f);   // RNE
    return *reinterpret_cast<unsigned short*>(&h);
}

// ---- prep (FIRST dispatch): zero gcur + bf16 W_nh + hi/lo split W_en ----
__global__ __launch_bounds__(256) void prep_w(
    const float* __restrict__ W_nh, const float* __restrict__ W_en,
    unsigned short* __restrict__ Wnh_bf,
    unsigned short* __restrict__ W1hi, unsigned short* __restrict__ W1lo,
    unsigned short* __restrict__ W2hi, unsigned short* __restrict__ W2lo,
    int* __restrict__ gcur)
{
    int idx = blockIdx.x * blockDim.x + threadIdx.x;
    if (idx < 2 * NBUCK) gcur[idx] = 0;       // replaces hipMemsetAsync dispatch
    if (idx < FDIM * FDIM) {
        Wnh_bf[idx] = f2bf(W_nh[idx]);
        return;
    }
    int j = idx - FDIM * FDIM;
    if (j >= 2 * FDIM * FDIM) return;
    int n = j >> 8, kk = j & 255;
    float w = W_en[n * 2 * FDIM + kk];
    unsigned short hi = f2bf(w);
    unsigned short lo = f2bf(w - bf2f(hi));
    int o = n * FDIM + (kk & 127);
    if (kk < FDIM) { W1hi[o] = hi; W1lo[o] = lo; }
    else           { W2hi[o] = hi; W2lo[o] = lo; }
}

// ---- GEMM1 via MFMA: out[100000,128] = sigmoid(x0 @ W_nh^T + b), bf16 out ----
__global__ __launch_bounds__(256) void gemm1_mfma(
    const float* __restrict__ x0, const unsigned short* __restrict__ Wb,
    const float* __restrict__ bias, unsigned short* __restrict__ out)
{
    __shared__ unsigned short As[32][FDIM + 8];
    const int tid  = threadIdx.x;
    const int row0 = blockIdx.x * 32;
    {
        int r = tid >> 3, c0 = (tid & 7) * 16;
        const float* src = x0 + (size_t)(row0 + r) * FDIM + c0;
        unsigned short* dst = &As[r][c0];
        #pragma unroll
        for (int i = 0; i < 4; i++) {
            float4 v = *(const float4*)(src + i * 4);
            dst[i * 4 + 0] = f2bf(v.x);
            dst[i * 4 + 1] = f2bf(v.y);
            dst[i * 4 + 2] = f2bf(v.z);
            dst[i * 4 + 3] = f2bf(v.w);
        }
    }
    __syncthreads();
    const int wave  = tid >> 6;
    const int lane  = tid & 63;
    const int mhalf = wave & 1;
    const int nhalf = wave >> 1;
    const int lm    = lane & 15;
    const int quad  = lane >> 4;
    f32x4_t acc[4] = {};
    #pragma unroll
    for (int ks = 0; ks < 4; ks++) {
        bf16x8_t a = *(const bf16x8_t*)&As[mhalf * 16 + lm][ks * 32 + quad * 8];
        #pragma unroll
        for (int nt = 0; nt < 4; nt++) {
            int n = nhalf * 64 + nt * 16 + lm;
            bf16x8_t b = *(const bf16x8_t*)(Wb + (size_t)n * FDIM + ks * 32 + quad * 8);
            acc[nt] = __builtin_amdgcn_mfma_f32_16x16x32_bf16(a, b, acc[nt], 0, 0, 0);
        }
    }
    const int mbase = row0 + mhalf * 16 + quad * 4;
    #pragma unroll
    for (int nt = 0; nt < 4; nt++) {
        int n = nhalf * 64 + nt * 16 + lm;
        float bv = bias[n];
        #pragma unroll
        for (int r2 = 0; r2 < 4; r2++) {
            out[(size_t)(mbase + r2) * FDIM + n] = f2bf(sigmoidf_(acc[nt][r2] + bv));
        }
    }
}

// ---- GEMM2 via MFMA + bf16 error-compensated splitting (R5 verified) ----
__global__ __launch_bounds__(256) void gemm2_mfma(
    const float* __restrict__ x1, const float* __restrict__ Bagg,
    const unsigned short* __restrict__ W1hi, const unsigned short* __restrict__ W1lo,
    const unsigned short* __restrict__ W2hi, const unsigned short* __restrict__ W2lo,
    const float* __restrict__ bias, unsigned short* __restrict__ out)
{
    __shared__ unsigned short Ax[2][32][FDIM + 8];   // x1 hi, lo
    __shared__ unsigned short Ab[2][32][FDIM + 8];   // B  hi, lo
    const int tid  = threadIdx.x;
    const int row0 = blockIdx.x * 32;
    {
        int r = tid >> 3, c0 = (tid & 7) * 16;
        const float* sx = x1   + (size_t)(row0 + r) * FDIM + c0;
        const float* sb = Bagg + (size_t)(row0 + r) * FDIM + c0;
        #pragma unroll
        for (int i = 0; i < 4; i++) {
            float4 v = *(const float4*)(sx + i * 4);
            float4 w = *(const float4*)(sb + i * 4);
            #pragma unroll
            for (int c = 0; c < 4; c++) {
                float fv = (c == 0) ? v.x : (c == 1) ? v.y : (c == 2) ? v.z : v.w;
                unsigned short h = f2bf(fv);
                Ax[0][r][c0 + i * 4 + c] = h;
                Ax[1][r][c0 + i * 4 + c] = f2bf(fv - bf2f(h));
                float fw = (c == 0) ? w.x : (c == 1) ? w.y : (c == 2) ? w.z : w.w;
                unsigned short hb = f2bf(fw);
                Ab[0][r][c0 + i * 4 + c] = hb;
                Ab[1][r][c0 + i * 4 + c] = f2bf(fw - bf2f(hb));
            }
        }
    }
    __syncthreads();
    const int wave  = tid >> 6;
    const int lane  = tid & 63;
    const int mhalf = wave & 1;
    const int nhalf = wave >> 1;
    const int lm    = lane & 15;
    const int quad  = lane >> 4;
    f32x4_t acc[4] = {};
    const unsigned short* Wsel[6] = {W1hi, W1hi, W1lo, W2hi, W2hi, W2lo};
    #pragma unroll
    for (int ps = 0; ps < 6; ps++) {
        const unsigned short (*Asel)[FDIM + 8] =
            (ps < 3) ? ((ps == 1) ? Ax[1] : Ax[0])
                     : ((ps == 4) ? Ab[1] : Ab[0]);
        const unsigned short* Wp = Wsel[ps];
        #pragma unroll
        for (int ks = 0; ks < 4; ks++) {
            bf16x8_t a = *(const bf16x8_t*)&Asel[mhalf * 16 + lm][ks * 32 + quad * 8];
            #pragma unroll
            for (int nt = 0; nt < 4; nt++) {
                int n = nhalf * 64 + nt * 16 + lm;
                bf16x8_t b = *(const bf16x8_t*)(Wp + (size_t)n * FDIM + ks * 32 + quad * 8);
                acc[nt] = __builtin_amdgcn_mfma_f32_16x16x32_bf16(a, b, acc[nt], 0, 0, 0);
            }
        }
    }
    const int mbase = row0 + mhalf * 16 + quad * 4;
    #pragma unroll
    for (int nt = 0; nt < 4; nt++) {
        int n = nhalf * 64 + nt * 16 + lm;
        float bv = bias[n];
        #pragma unroll
        for (int r2 = 0; r2 < 4; r2++) {
            out[(size_t)(mbase + r2) * FDIM + n] = f2bf(sigmoidf_(acc[nt][r2] + bv));
        }
    }
}

// ---- Pass A: coarse bucket partition (both directions in one pass) ----
__global__ __launch_bounds__(1024) void bucket_scatter(
    const int* __restrict__ ni, const int* __restrict__ ei,
    unsigned* __restrict__ buck_e, unsigned* __restrict__ buck_n,
    int* __restrict__ gcur_e, int* __restrict__ gcur_n)
{
    __shared__ int lh_e[NBUCK], lh_n[NBUCK], lb_e[NBUCK], lb_n[NBUCK];
    const int t = threadIdx.x;
    if (t < NBUCK) { lh_e[t] = 0; lh_n[t] = 0; }
    __syncthreads();
    unsigned ent_e[4], ent_n[4];
    int be[4], bn[4], re[4], rn[4];
    const int base = blockIdx.x * 4096;
    #pragma unroll
    for (int j = 0; j < 4; j++) {
        int i = base + j * 1024 + t;
        if (i < NNZ_) {
            unsigned n = (unsigned)ni[i], e = (unsigned)ei[i];
            ent_e[j] = (e << SH_E) | n;  be[j] = (int)(e / BPB_E);
            ent_n[j] = (n << SH_N) | e;  bn[j] = (int)(n / BPB_N);
            re[j] = atomicAdd(&lh_e[be[j]], 1);
            rn[j] = atomicAdd(&lh_n[bn[j]], 1);
        } else { be[j] = -1; }
    }
    __syncthreads();
    if (t < NBUCK) {
        lb_e[t] = t * CAP + atomicAdd(&gcur_e[t], lh_e[t]);
        lb_n[t] = t * CAP + atomicAdd(&gcur_n[t], lh_n[t]);
    }
    __syncthreads();
    #pragma unroll
    for (int j = 0; j < 4; j++) {
        if (be[j] >= 0) {
            buck_e[(size_t)lb_e[be[j]] + re[j]] = ent_e[j];
            buck_n[(size_t)lb_n[bn[j]] + rn[j]] = ent_n[j];
        }
    }
}

// ---- Pass B, edge dir: sort bucket into (e,p)-bins; p = n/PSLICE ----
__device__ __forceinline__ int ep_bin(unsigned ent) {
    int e = (int)(ent >> SH_E);
    int n = (int)(ent & 0x1FFFFu);
    return e * NPART + n / PSLICE;
}

__device__ __forceinline__ void sort_bucket_e(
    const unsigned* __restrict__ region, int cnt, int gbase, int bucket,
    unsigned* __restrict__ csr, int* __restrict__ off)
{
    __shared__ unsigned lh[768];
    __shared__ unsigned lw[4];
    const int t = threadIdx.x;
    lh[t] = 0; lh[t + 256] = 0; lh[t + 512] = 0;
    __syncthreads();
    const int b0 = bucket * (BPB_E * NPART);
    for (int i = t; i < cnt; i += 256)
        atomicAdd(&lh[ep_bin(region[i]) - b0], 1u);
    __syncthreads();
    unsigned h0 = lh[3 * t], h1 = lh[3 * t + 1], h2 = lh[3 * t + 2];
    unsigned s = h0 + h1 + h2, inc = s;
    const int lane = t & 63;
    #pragma unroll
    for (int d = 1; d <= 32; d <<= 1) {
        unsigned v = (unsigned)__shfl_up((int)inc, d, 64);
        if (lane >= d) inc += v;
    }
    if (lane == 63) lw[t >> 6] = inc;
    __syncthreads();
    unsigned pre = 0;
    #pragma unroll
    for (int w = 0; w < 4; w++) if (w < (t >> 6)) pre += lw[w];
    unsigned excl = pre + inc - s;
    unsigned c0 = (unsigned)gbase + excl, c1 = c0 + h0, c2 = c1 + h1;
    lh[3 * t] = c0; lh[3 * t + 1] = c1; lh[3 * t + 2] = c2;
    #pragma unroll
    for (int j = 0; j < 3; j++) {
        int ib = 3 * t + j;
        unsigned cc = (j == 0) ? c0 : (j == 1) ? c1 : c2;
        if (ib <= BPB_E * NPART && b0 + ib <= NEDGES * NPART) off[b0 + ib] = (int)cc;
    }
    __syncthreads();
    for (int i = t; i < cnt; i += 256) {
        unsigned ent = region[i];
        unsigned pos = atomicAdd(&lh[ep_bin(ent) - b0], 1u);
        csr[pos] = ent & 0x1FFFFu;
    }
}

// ---- Pass B, node dir: 2 bins/thread ----
__device__ __forceinline__ void sort_bucket_n(
    const unsigned* __restrict__ region, int cnt, int gbase, int b0,
    unsigned short* __restrict__ csr, int* __restrict__ off)
{
    __shared__ unsigned lh[512];
    __shared__ unsigned lw[4];
    const int t = threadIdx.x;
    lh[t] = 0; lh[t + 256] = 0;
    __syncthreads();
    for (int i = t; i < cnt; i += 256) {
        int bin = (int)(region[i] >> SH_N) - b0;
        atomicAdd(&lh[bin], 1u);
    }
    __syncthreads();
    unsigned h0 = lh[2 * t], h1 = lh[2 * t + 1];
    unsigned s = h0 + h1, inc = s;
    const int lane = t & 63;
    #pragma unroll
    for (int d = 1; d <= 32; d <<= 1) {
        unsigned v = (unsigned)__shfl_up((int)inc, d, 64);
        if (lane >= d) inc += v;
    }
    if (lane == 63) lw[t >> 6] = inc;
    __syncthreads();
    unsigned pre = 0;
    #pragma unroll
    for (int w = 0; w < 4; w++) if (w < (t >> 6)) pre += lw[w];
    unsigned excl = pre + inc - s;
    unsigned c0 = (unsigned)gbase + excl;
    unsigned c1 = c0 + h0;
    lh[2 * t] = c0; lh[2 * t + 1] = c1;
    int i0 = 2 * t, i1 = 2 * t + 1;
    if (i0 <= BPB_N && b0 + i0 <= NNODES) off[b0 + i0] = (int)c0;
    if (i1 <= BPB_N && b0 + i1 <= NNODES) off[b0 + i1] = (int)c1;
    __syncthreads();
    for (int i = t; i < cnt; i += 256) {
        unsigned ent = region[i];
        int bin = (int)(ent >> SH_N) - b0;
        unsigned pos = atomicAdd(&lh[bin], 1u);
        csr[pos] = (unsigned short)(ent & 0x7FFFu);
    }
}

__global__ __launch_bounds__(256) void bucket_sort(
    const unsigned* __restrict__ buck_e, const unsigned* __restrict__ buck_n,
    const int* __restrict__ gcur_e, const int* __restrict__ gcur_n,
    unsigned* __restrict__ csr_e, unsigned short* __restrict__ csr_n,
    int* __restrict__ off_ep, int* __restrict__ off_n)
{
    const int b = blockIdx.x & 255;
    const int* gc = (blockIdx.x < 256) ? gcur_e : gcur_n;
    __shared__ int ws4[4];
    const int t = threadIdx.x;
    int v = (t < b) ? gc[t] : 0;
    #pragma unroll
    for (int d = 32; d > 0; d >>= 1) v += __shfl_down(v, d, 64);
    if ((t & 63) == 0) ws4[t >> 6] = v;
    __syncthreads();
    const int gbase = ws4[0] + ws4[1] + ws4[2] + ws4[3];
    const int cnt = gc[b];
    __syncthreads();
    if (blockIdx.x < 256)
        sort_bucket_e(buck_e + (size_t)b * CAP, cnt, gbase, b, csr_e, off_ep);
    else
        sort_bucket_n(buck_n + (size_t)b * CAP, cnt, gbase, b * BPB_N, csr_n, off_n);
}

// ---- XCD-affine partial gather (R4 lean, no nt): wave=(e,p), blockIdx=c*8+p ----
__global__ __launch_bounds__(256) void seg_part_gather(
    const unsigned short* __restrict__ table, const unsigned* __restrict__ csr,
    const int* __restrict__ off_ep, float* __restrict__ partial)
{
    const int p = blockIdx.x & 7;
    const int e = (blockIdx.x >> 3) * 4 + (threadIdx.x >> 6);
    const int lane = threadIdx.x & 63;
    const int sub  = lane >> 4;
    const int c8   = (lane & 15) * 8;
    const int bin  = e * NPART + p;
    const int i0 = off_ep[bin], i1 = off_ep[bin + 1];
    f32x4_t a0 = {}, a1 = {};
    int i = i0;
    for (; i + 8 <= i1; i += 8) {
        int r0 = (int)csr[i + sub];
        int r1 = (int)csr[i + 4 + sub];
        u16x8_t v0 = *(const u16x8_t*)(table + (size_t)r0 * FDIM + c8);
        u16x8_t v1 = *(const u16x8_t*)(table + (size_t)r1 * FDIM + c8);
        a0[0] += bf2f(v0[0]) + bf2f(v1[0]);
        a0[1] += bf2f(v0[1]) + bf2f(v1[1]);
        a0[2] += bf2f(v0[2]) + bf2f(v1[2]);
        a0[3] += bf2f(v0[3]) + bf2f(v1[3]);
        a1[0] += bf2f(v0[4]) + bf2f(v1[4]);
        a1[1] += bf2f(v0[5]) + bf2f(v1[5]);
        a1[2] += bf2f(v0[6]) + bf2f(v1[6]);
        a1[3] += bf2f(v0[7]) + bf2f(v1[7]);
    }
    if (i + 4 <= i1) {
        int r = (int)csr[i + sub];
        u16x8_t v = *(const u16x8_t*)(table + (size_t)r * FDIM + c8);
        a0[0] += bf2f(v[0]); a0[1] += bf2f(v[1]);
        a0[2] += bf2f(v[2]); a0[3] += bf2f(v[3]);
        a1[0] += bf2f(v[4]); a1[1] += bf2f(v[5]);
        a1[2] += bf2f(v[6]); a1[3] += bf2f(v[7]);
        i += 4;
    }
    if (i < i1 && sub < i1 - i) {
        int r = (int)csr[i + sub];
        u16x8_t v = *(const u16x8_t*)(table + (size_t)r * FDIM + c8);
        a0[0] += bf2f(v[0]); a0[1] += bf2f(v[1]);
        a0[2] += bf2f(v[2]); a0[3] += bf2f(v[3]);
        a1[0] += bf2f(v[4]); a1[1] += bf2f(v[5]);
        a1[2] += bf2f(v[6]); a1[3] += bf2f(v[7]);
    }
    #pragma unroll
    for (int j = 0; j < 4; j++) {
        a0[j] += __shfl_xor(a0[j], 16, 64);
        a0[j] += __shfl_xor(a0[j], 32, 64);
        a1[j] += __shfl_xor(a1[j], 16, 64);
        a1[j] += __shfl_xor(a1[j], 32, 64);
    }
    if (sub < 2) {
        const int q = c8 + sub * 4;
        f32x4_t s = sub ? a1 : a0;
        *(f32x4_t*)(partial + ((size_t)p * NEDGES + e) * FDIM + q) = s;
    }
}

// ---- streaming 8-way partial reduce + B write + fused out1 finalize (R4) ----
__global__ __launch_bounds__(256) void reduce_fin(
    const float* __restrict__ part, const float* __restrict__ x1,
    const float* __restrict__ g, const float* __restrict__ bb,
    const float* __restrict__ mm, const float* __restrict__ vv,
    float* __restrict__ B, float* __restrict__ out1)
{
    const int idx = blockIdx.x * 256 + threadIdx.x;   // one f32x4 per thread
    if (idx >= NEDGES * (FDIM / 4)) return;
    const size_t q = (size_t)idx * 4;
    f32x4_t s = {};
    #pragma unroll
    for (int p = 0; p < NPART; p++)
        s += __builtin_nontemporal_load(
                 (const f32x4_t*)(part + (size_t)p * NEDGES * FDIM + q));
    *(f32x4_t*)(B + q) = s;
    const int col = (idx & 31) * 4;
    f32x4_t xv = *(const f32x4_t*)(x1 + q);
    f32x4_t gg = *(const f32x4_t*)(g + col);
    f32x4_t bt = *(const f32x4_t*)(bb + col);
    f32x4_t mn = *(const f32x4_t*)(mm + col);
    f32x4_t vr = *(const f32x4_t*)(vv + col);
    f32x4_t o;
    #pragma unroll
    for (int j = 0; j < 4; j++)
        o[j] = sigmoidf_((xv[j] - mn[j]) * (gg[j] * rsqrtf(vr[j] + BN_EPS))
                         + bt[j] + s[j]);
    __builtin_nontemporal_store(o, (f32x4_t*)(out1 + q));
}

// ---- segmented sum v2 (node dir + edge fallback): one wave/segment, U-deep ----
template<typename IDX, int U, int OFFSTR>
__global__ __launch_bounds__(256) void seg_sum_fin_v2(
    const unsigned short* __restrict__ table, const IDX* __restrict__ csr,
    const int* __restrict__ off, const float* __restrict__ x,
    const float* __restrict__ g, const float* __restrict__ bb,
    const float* __restrict__ mm, const float* __restrict__ vv,
    float* __restrict__ agg_out, float* __restrict__ fin_out, int nseg)
{
    const int seg = blockIdx.x * 4 + (threadIdx.x >> 6);
    if (seg >= nseg) return;
    const int lane = threadIdx.x & 63;
    const int c    = lane & 15;
    const int sub  = lane >> 4;
    const int c8   = c * 8;

    const int i0 = off[seg * OFFSTR], i1 = off[seg * OFFSTR + OFFSTR];
    f32x4_t a0 = {}, a1 = {};

    int i = i0;
    for (; i + 4 * U <= i1; i += 4 * U) {
        int r[U];
        u16x8_t v[U];
        #pragma unroll
        for (int u = 0; u < U; u++) r[u] = (int)csr[i + 4 * u + sub];
        #pragma unroll
        for (int u = 0; u < U; u++)
            v[u] = *(const u16x8_t*)(table + (size_t)r[u] * FDIM + c8);
        #pragma unroll
        for (int u = 0; u < U; u++) {
            a0[0] += bf2f(v[u][0]); a0[1] += bf2f(v[u][1]);
            a0[2] += bf2f(v[u][2]); a0[3] += bf2f(v[u][3]);
            a1[0] += bf2f(v[u][4]); a1[1] += bf2f(v[u][5]);
            a1[2] += bf2f(v[u][6]); a1[3] += bf2f(v[u][7]);
        }
    }
    if (i < i1) {
        u16x8_t v[U];
        #pragma unroll
        for (int u = 0; u < U; u++) {
            int row = i + 4 * u + sub;
            u16x8_t z = {};
            v[u] = z;
            if (row < i1)
                v[u] = *(const u16x8_t*)(table + (size_t)csr[row] * FDIM + c8);
        }
        #pragma unroll
        for (int u = 0; u < U; u++) {
            a0[0] += bf2f(v[u][0]); a0[1] += bf2f(v[u][1]);
            a0[2] += bf2f(v[u][2]); a0[3] += bf2f(v[u][3]);
            a1[0] += bf2f(v[u][4]); a1[1] += bf2f(v[u][5]);
            a1[2] += bf2f(v[u][6]); a1[3] += bf2f(v[u][7]);
        }
    }

    #pragma unroll
    for (int j = 0; j < 4; j++) {
        a0[j] += __shfl_xor(a0[j], 16, 64);
        a0[j] += __shfl_xor(a0[j], 32, 64);
        a1[j] += __shfl_xor(a1[j], 16, 64);
        a1[j] += __shfl_xor(a1[j], 32, 64);
    }

    if (sub < 2) {
        const int q = c8 + sub * 4;
        f32x4_t s = sub ? a1 : a0;
        if (agg_out)
            *(f32x4_t*)(agg_out + (size_t)seg * FDIM + q) = s;
        if (fin_out) {
            f32x4_t xv = *(const f32x4_t*)(x + (size_t)seg * FDIM + q);
            f32x4_t gg = *(const f32x4_t*)(g + q);
            f32x4_t bt = *(const f32x4_t*)(bb + q);
            f32x4_t mn = *(const f32x4_t*)(mm + q);
            f32x4_t vr = *(const f32x4_t*)(vv + q);
            f32x4_t o;
            #pragma unroll
            for (int j = 0; j < 4; j++)
                o[j] = sigmoidf_((xv[j] - mn[j]) * (gg[j] * rsqrtf(vr[j] + BN_EPS))
                                 + bt[j] + s[j]);
            *(f32x4_t*)(fin_out + (size_t)seg * FDIM + q) = o;
        }
    }
}

extern "C" void kernel_launch(void* const* d_in, const int* in_sizes, int n_in,
                              void* d_out, int out_size, void* d_ws, size_t ws_size,
                              hipStream_t stream)
{
    const float* x0       = (const float*)d_in[0];
    const float* x1       = (const float*)d_in[1];
    const int*   node_idx = (const int*)d_in[2];
    const int*   edge_idx = (const int*)d_in[3];
    const float* W_nh     = (const float*)d_in[4];
    const float* b_nh     = (const float*)d_in[5];
    const float* W_en     = (const float*)d_in[6];
    const float* b_en     = (const float*)d_in[7];
    const float* bn0g = (const float*)d_in[8];
    const float* bn0b = (const float*)d_in[9];
    const float* bn0m = (const float*)d_in[10];
    const float* bn0v = (const float*)d_in[11];
    const float* bn1g = (const float*)d_in[12];
    const float* bn1b = (const float*)d_in[13];
    const float* bn1m = (const float*)d_in[14];
    const float* bn1v = (const float*)d_in[15];

    float* ws = (float*)d_ws;
    float* B = ws;                                        // [20000,128] fp32
    unsigned short* Wnh_bf = (unsigned short*)(B + (size_t)NEDGES * FDIM);
    unsigned short* W1hi = Wnh_bf + FDIM * FDIM;
    unsigned short* W1lo = W1hi + FDIM * FDIM;
    unsigned short* W2hi = W1lo + FDIM * FDIM;
    unsigned short* W2lo = W2hi + FDIM * FDIM;
    unsigned short* A_bf = W2lo + FDIM * FDIM;            // [100000,128] bf16
    unsigned short* D_bf = A_bf + (size_t)NNODES * FDIM;  // [20000,128] bf16
    int* off_ep = (int*)(D_bf + (size_t)NEDGES * FDIM);   // 160001 (pad 160004)
    int* off_n  = off_ep + 160004;                        // 100001 (pad 100004)
    unsigned* csr_e = (unsigned*)(off_n + 100004);        // 2M u32
    unsigned short* csr_n = (unsigned short*)(csr_e + NNZ_); // 2M u16
    unsigned* buck_e = (unsigned*)(csr_n + NNZ_);         // [NBUCK*CAP]
    unsigned* buck_n = buck_e + (size_t)NBUCK * CAP;      // [NBUCK*CAP]
    int* gcur_e = (int*)(buck_n + (size_t)NBUCK * CAP);   // 256
    int* gcur_n = gcur_e + NBUCK;                         // 256
    // partials overlay the (dead-after-sort) bucket arrays: [8][20000][128] fp32
    float* partial = (float*)buck_e;
    const size_t need = ((char*)partial - (char*)d_ws)
                      + (size_t)NPART * NEDGES * FDIM * sizeof(float);
    const bool big = ws_size >= need;

    // prep first: zeroes gcur (replaces memset dispatch) + W conversions/splits
    prep_w<<<(3 * FDIM * FDIM + 255) / 256, 256, 0, stream>>>(
        W_nh, W_en, Wnh_bf, W1hi, W1lo, W2hi, W2lo, gcur_e);

    // --- CSR build via 2-level bucket sort (edge dir binned by (e, n/PSLICE)) ---
    bucket_scatter<<<(NNZ_ + 4095) / 4096, 1024, 0, stream>>>(
        node_idx, edge_idx, buck_e, buck_n, gcur_e, gcur_n);
    bucket_sort<<<2 * NBUCK, 256, 0, stream>>>(buck_e, buck_n, gcur_e, gcur_n,
                                               csr_e, csr_n, off_ep, off_n);

    float* out0 = (float*)d_out;
    float* out1 = out0 + (size_t)NNODES * FDIM;

    // node -> hyperedge: GEMM1 (MFMA, bf16 out)
    gemm1_mfma<<<NNODES / 32, 256, 0, stream>>>(x0, Wnh_bf, b_nh, A_bf);

    if (big) {
        // XCD-affine partial gather -> streaming reduce (+ out1 finalize)
        seg_part_gather<<<(NEDGES / 4) * 8, 256, 0, stream>>>(
            A_bf, csr_e, off_ep, partial);
        reduce_fin<<<(NEDGES * (FDIM / 4) + 255) / 256, 256, 0, stream>>>(
            partial, x1, bn1g, bn1b, bn1m, bn1v, B, out1);
    } else {
        // fallback: edge segments span 8 adjacent bins of off_ep
        seg_sum_fin_v2<unsigned, 8, NPART><<<(NEDGES + 3) / 4, 256, 0, stream>>>(
            A_bf, csr_e, off_ep, x1, bn1g, bn1b, bn1m, bn1v, B, out1, NEDGES);
    }

    // hyperedge -> node: GEMM2 (MFMA, split-bf16) then pull-aggregate (+ x0_out)
    gemm2_mfma<<<NEDGES / 32, 256, 0, stream>>>(
        x1, B, W1hi, W1lo, W2hi, W2lo, b_en, D_bf);
    seg_sum_fin_v2<unsigned short, 4, 1><<<(NNODES + 3) / 4, 256, 0, stream>>>(
        D_bf, csr_n, off_n, x0, bn0g, bn0b, bn0m, bn0v, nullptr, out0, NNODES);
}

// Round 8
// 393.766 us; speedup vs baseline: 1.0159x; 1.0159x over previous
//
#include <hip/hip_runtime.h>
#include <hip/hip_bf16.h>
#include <math.h>

#define NNODES 100000
#define NEDGES 20000
#define NNZ_   2000000
#define FDIM   128
#define BN_EPS 1e-5f

// ---- bucket-sort geometry (R1/R5 verified) ----
#define NBUCK 256
#define CAP   9216        // per-bucket capacity (mean ~7812, sigma ~88 -> +16 sigma)
#define BPB_E 79          // bins/bucket, edge dir
#define BPB_N 391         // bins/bucket, node dir
#define SH_E  17          // edge entry = (e<<17)|n
#define SH_N  15          // node entry = (n<<15)|e

typedef __attribute__((ext_vector_type(8))) short bf16x8_t;
typedef __attribute__((ext_vector_type(4))) float f32x4_t;
typedef __attribute__((ext_vector_type(8))) unsigned short u16x8_t;

__device__ __forceinline__ float sigmoidf_(float x) {
    return 1.0f / (1.0f + __expf(-x));
}
__device__ __forceinline__ float bf2f(unsigned short u) {
    return __uint_as_float(((unsigned)u) << 16);
}
__device__ __forceinline__ unsigned short f2bf(float f) {
    __hip_bfloat16 h = __float2bfloat16(f);   // RNE
    return *reinterpret_cast<unsigned short*>(&h);
}

// ---- prep (FIRST dispatch): zero gcur + bf16 W_nh + hi/lo split W_en ----
__global__ __launch_bounds__(256) void prep_w(
    const float* __restrict__ W_nh, const float* __restrict__ W_en,
    unsigned short* __restrict__ Wnh_bf,
    unsigned short* __restrict__ W1hi, unsigned short* __restrict__ W1lo,
    unsigned short* __restrict__ W2hi, unsigned short* __restrict__ W2lo,
    int* __restrict__ gcur)
{
    int idx = blockIdx.x * blockDim.x + threadIdx.x;
    if (idx < 2 * NBUCK) gcur[idx] = 0;
    if (idx < FDIM * FDIM) {
        Wnh_bf[idx] = f2bf(W_nh[idx]);
        return;
    }
    int j = idx - FDIM * FDIM;
    if (j >= 2 * FDIM * FDIM) return;
    int n = j >> 8, kk = j & 255;
    float w = W_en[n * 2 * FDIM + kk];
    unsigned short hi = f2bf(w);
    unsigned short lo = f2bf(w - bf2f(hi));
    int o = n * FDIM + (kk & 127);
    if (kk < FDIM) { W1hi[o] = hi; W1lo[o] = lo; }
    else           { W2hi[o] = hi; W2lo[o] = lo; }
}

// ---- register-resident GEMM1 tile: 32 rows x 128 cols, no LDS, no barriers ----
// wave = 16 rows x 64 cols; A-fragment loaded straight from global x0.
__device__ __forceinline__ void gemm1_tile(
    const float* __restrict__ x0, const unsigned short* __restrict__ Wb,
    const float* __restrict__ bias, unsigned short* __restrict__ out,
    int row0, int tid)
{
    const int wave  = tid >> 6;
    const int lane  = tid & 63;
    const int mhalf = wave & 1;
    const int nhalf = wave >> 1;
    const int lm    = lane & 15;
    const int quad  = lane >> 4;
    const float* ar = x0 + (size_t)(row0 + mhalf * 16 + lm) * FDIM;
    f32x4_t acc[4] = {};
    #pragma unroll
    for (int ks = 0; ks < 4; ks++) {
        const int ko = ks * 32 + quad * 8;
        float4 f0 = *(const float4*)(ar + ko);
        float4 f1 = *(const float4*)(ar + ko + 4);
        bf16x8_t a;
        a[0] = (short)f2bf(f0.x); a[1] = (short)f2bf(f0.y);
        a[2] = (short)f2bf(f0.z); a[3] = (short)f2bf(f0.w);
        a[4] = (short)f2bf(f1.x); a[5] = (short)f2bf(f1.y);
        a[6] = (short)f2bf(f1.z); a[7] = (short)f2bf(f1.w);
        #pragma unroll
        for (int nt = 0; nt < 4; nt++) {
            int n = nhalf * 64 + nt * 16 + lm;
            bf16x8_t b = *(const bf16x8_t*)(Wb + (size_t)n * FDIM + ko);
            acc[nt] = __builtin_amdgcn_mfma_f32_16x16x32_bf16(a, b, acc[nt], 0, 0, 0);
        }
    }
    const int mbase = row0 + mhalf * 16 + quad * 4;
    #pragma unroll
    for (int nt = 0; nt < 4; nt++) {
        int n = nhalf * 64 + nt * 16 + lm;
        float bv = bias[n];
        #pragma unroll
        for (int r2 = 0; r2 < 4; r2++) {
            out[(size_t)(mbase + r2) * FDIM + n] = f2bf(sigmoidf_(acc[nt][r2] + bv));
        }
    }
}

// ---- fused dispatch: blocks [0,nscatter) = bucket_scatter, rest = gemm1 ----
// Independent work (scatter: ni/ei -> buckets; gemm1: x0 -> A_bf) overlapped.
__global__ __launch_bounds__(1024) void scatter_gemm1(
    const int* __restrict__ ni, const int* __restrict__ ei,
    unsigned* __restrict__ buck_e, unsigned* __restrict__ buck_n,
    int* __restrict__ gcur_e, int* __restrict__ gcur_n,
    const float* __restrict__ x0, const unsigned short* __restrict__ Wb,
    const float* __restrict__ bias, unsigned short* __restrict__ A_bf,
    int nscatter)
{
    if (blockIdx.x < nscatter) {
        __shared__ int lh_e[NBUCK], lh_n[NBUCK], lb_e[NBUCK], lb_n[NBUCK];
        const int t = threadIdx.x;
        if (t < NBUCK) { lh_e[t] = 0; lh_n[t] = 0; }
        __syncthreads();
        unsigned ent_e[4], ent_n[4];
        int be[4], bn[4], re[4], rn[4];
        const int base = blockIdx.x * 4096;
        #pragma unroll
        for (int j = 0; j < 4; j++) {
            int i = base + j * 1024 + t;
            if (i < NNZ_) {
                unsigned n = (unsigned)ni[i], e = (unsigned)ei[i];
                ent_e[j] = (e << SH_E) | n;  be[j] = (int)(e / BPB_E);
                ent_n[j] = (n << SH_N) | e;  bn[j] = (int)(n / BPB_N);
                re[j] = atomicAdd(&lh_e[be[j]], 1);
                rn[j] = atomicAdd(&lh_n[bn[j]], 1);
            } else { be[j] = -1; }
        }
        __syncthreads();
        if (t < NBUCK) {
            lb_e[t] = t * CAP + atomicAdd(&gcur_e[t], lh_e[t]);
            lb_n[t] = t * CAP + atomicAdd(&gcur_n[t], lh_n[t]);
        }
        __syncthreads();
        #pragma unroll
        for (int j = 0; j < 4; j++) {
            if (be[j] >= 0) {
                buck_e[(size_t)lb_e[be[j]] + re[j]] = ent_e[j];
                buck_n[(size_t)lb_n[bn[j]] + rn[j]] = ent_n[j];
            }
        }
    } else {
        // 1024 threads = 4 independent 32-row tiles (no barriers inside)
        const int bid  = blockIdx.x - nscatter;
        const int row0 = bid * 128 + (threadIdx.x >> 8) * 32;
        if (row0 >= NNODES) return;
        gemm1_tile(x0, Wb, bias, A_bf, row0, threadIdx.x & 255);
    }
}

// ---- GEMM2 register-resident: no LDS, 6-pass hi/lo split, fp32 acc ----
// grid: (NEDGES/32)*2 blocks; block covers 32 rows x 64 cols; wave = 16x32.
__device__ __forceinline__ void mfma_pass2(
    const bf16x8_t af[4], const unsigned short* __restrict__ W,
    int ncol, int lm, int quad, f32x4_t acc[2])
{
    #pragma unroll
    for (int ks = 0; ks < 4; ks++) {
        #pragma unroll
        for (int nt = 0; nt < 2; nt++) {
            int n = ncol + nt * 16 + lm;
            bf16x8_t b = *(const bf16x8_t*)(W + (size_t)n * FDIM + ks * 32 + quad * 8);
            acc[nt] = __builtin_amdgcn_mfma_f32_16x16x32_bf16(af[ks], b, acc[nt], 0, 0, 0);
        }
    }
}

__global__ __launch_bounds__(256) void gemm2_reg(
    const float* __restrict__ x1, const float* __restrict__ Bagg,
    const unsigned short* __restrict__ W1hi, const unsigned short* __restrict__ W1lo,
    const unsigned short* __restrict__ W2hi, const unsigned short* __restrict__ W2lo,
    const float* __restrict__ bias, unsigned short* __restrict__ out)
{
    const int row0 = (blockIdx.x >> 1) * 32;
    const int col0 = (blockIdx.x & 1) * 64;
    const int tid  = threadIdx.x;
    const int wave  = tid >> 6;
    const int lane  = tid & 63;
    const int mhalf = wave & 1;
    const int npair = wave >> 1;          // 0..1 -> 32-col slice
    const int lm    = lane & 15;
    const int quad  = lane >> 4;
    const int rowA  = row0 + mhalf * 16 + lm;
    const float* xr = x1   + (size_t)rowA * FDIM;
    const float* br = Bagg + (size_t)rowA * FDIM;

    bf16x8_t axh[4], axl[4], abh[4], abl[4];
    #pragma unroll
    for (int ks = 0; ks < 4; ks++) {
        const int ko = ks * 32 + quad * 8;
        float4 f0 = *(const float4*)(xr + ko);
        float4 f1 = *(const float4*)(xr + ko + 4);
        float4 g0 = *(const float4*)(br + ko);
        float4 g1 = *(const float4*)(br + ko + 4);
        float fx[8] = {f0.x, f0.y, f0.z, f0.w, f1.x, f1.y, f1.z, f1.w};
        float fb[8] = {g0.x, g0.y, g0.z, g0.w, g1.x, g1.y, g1.z, g1.w};
        #pragma unroll
        for (int j = 0; j < 8; j++) {
            unsigned short h = f2bf(fx[j]);
            axh[ks][j] = (short)h;
            axl[ks][j] = (short)f2bf(fx[j] - bf2f(h));
            unsigned short hb = f2bf(fb[j]);
            abh[ks][j] = (short)hb;
            abl[ks][j] = (short)f2bf(fb[j] - bf2f(hb));
        }
    }

    f32x4_t acc[2] = {};
    const int ncol = col0 + npair * 32;
    mfma_pass2(axh, W1hi, ncol, lm, quad, acc);
    mfma_pass2(axl, W1hi, ncol, lm, quad, acc);
    mfma_pass2(axh, W1lo, ncol, lm, quad, acc);
    mfma_pass2(abh, W2hi, ncol, lm, quad, acc);
    mfma_pass2(abl, W2hi, ncol, lm, quad, acc);
    mfma_pass2(abh, W2lo, ncol, lm, quad, acc);

    const int mbase = row0 + mhalf * 16 + quad * 4;
    #pragma unroll
    for (int nt = 0; nt < 2; nt++) {
        int n = ncol + nt * 16 + lm;
        float bv = bias[n];
        #pragma unroll
        for (int r2 = 0; r2 < 4; r2++) {
            out[(size_t)(mbase + r2) * FDIM + n] = f2bf(sigmoidf_(acc[nt][r2] + bv));
        }
    }
}

// ---- Pass B: sort one bucket into its compact region (R1/R5 verified) ----
template<int BPB, int SH, unsigned MASK, int NBINS, typename OUT>
__device__ __forceinline__ void sort_bucket(
    const unsigned* __restrict__ region, int cnt, int gbase, int b0,
    OUT* __restrict__ csr, int* __restrict__ off)
{
    __shared__ unsigned lh[512];
    __shared__ unsigned lw[4];
    const int t = threadIdx.x;
    lh[t] = 0; lh[t + 256] = 0;
    __syncthreads();
    for (int i = t; i < cnt; i += 256) {
        int bin = (int)(region[i] >> SH) - b0;
        atomicAdd(&lh[bin], 1u);
    }
    __syncthreads();
    unsigned h0 = lh[2 * t], h1 = lh[2 * t + 1];
    unsigned s = h0 + h1, inc = s;
    const int lane = t & 63;
    #pragma unroll
    for (int d = 1; d <= 32; d <<= 1) {
        unsigned v = (unsigned)__shfl_up((int)inc, d, 64);
        if (lane >= d) inc += v;
    }
    if (lane == 63) lw[t >> 6] = inc;
    __syncthreads();
    unsigned pre = 0;
    #pragma unroll
    for (int w = 0; w < 4; w++) if (w < (t >> 6)) pre += lw[w];
    unsigned excl = pre + inc - s;
    unsigned c0 = (unsigned)gbase + excl;
    unsigned c1 = c0 + h0;
    lh[2 * t] = c0; lh[2 * t + 1] = c1;
    int i0 = 2 * t, i1 = 2 * t + 1;
    if (i0 <= BPB && b0 + i0 <= NBINS) off[b0 + i0] = (int)c0;
    if (i1 <= BPB && b0 + i1 <= NBINS) off[b0 + i1] = (int)c1;
    __syncthreads();
    for (int i = t; i < cnt; i += 256) {
        unsigned ent = region[i];
        int bin = (int)(ent >> SH) - b0;
        unsigned pos = atomicAdd(&lh[bin], 1u);
        csr[pos] = (OUT)(ent & MASK);
    }
}

__global__ __launch_bounds__(256) void bucket_sort(
    const unsigned* __restrict__ buck_e, const unsigned* __restrict__ buck_n,
    const int* __restrict__ gcur_e, const int* __restrict__ gcur_n,
    unsigned* __restrict__ csr_e, unsigned short* __restrict__ csr_n,
    int* __restrict__ off_e, int* __restrict__ off_n)
{
    const int b = blockIdx.x & 255;
    const int* gc = (blockIdx.x < 256) ? gcur_e : gcur_n;
    __shared__ int ws4[4];
    const int t = threadIdx.x;
    int v = (t < b) ? gc[t] : 0;
    #pragma unroll
    for (int d = 32; d > 0; d >>= 1) v += __shfl_down(v, d, 64);
    if ((t & 63) == 0) ws4[t >> 6] = v;
    __syncthreads();
    const int gbase = ws4[0] + ws4[1] + ws4[2] + ws4[3];
    const int cnt = gc[b];
    __syncthreads();
    if (blockIdx.x < 256)
        sort_bucket<BPB_E, SH_E, 0x1FFFFu, NEDGES, unsigned>(
            buck_e + (size_t)b * CAP, cnt, gbase, b * BPB_E, csr_e, off_e);
    else
        sort_bucket<BPB_N, SH_N, 0x7FFFu, NNODES, unsigned short>(
            buck_n + (size_t)b * CAP, cnt, gbase, b * BPB_N, csr_n, off_n);
}

// ---- segmented sum v2: one wave per segment, 16B gathers, deep ILP (R5) ----
template<typename IDX, int U>
__global__ __launch_bounds__(256) void seg_sum_fin_v2(
    const unsigned short* __restrict__ table, const IDX* __restrict__ csr,
    const int* __restrict__ off, const float* __restrict__ x,
    const float* __restrict__ g, const float* __restrict__ bb,
    const float* __restrict__ mm, const float* __restrict__ vv,
    float* __restrict__ agg_out, float* __restrict__ fin_out, int nseg)
{
    const int seg = blockIdx.x * 4 + (threadIdx.x >> 6);
    if (seg >= nseg) return;
    const int lane = threadIdx.x & 63;
    const int c    = lane & 15;
    const int sub  = lane >> 4;
    const int c8   = c * 8;

    const int i0 = off[seg], i1 = off[seg + 1];
    f32x4_t a0 = {}, a1 = {};

    int i = i0;
    for (; i + 4 * U <= i1; i += 4 * U) {
        int r[U];
        u16x8_t v[U];
        #pragma unroll
        for (int u = 0; u < U; u++) r[u] = (int)csr[i + 4 * u + sub];
        #pragma unroll
        for (int u = 0; u < U; u++)
            v[u] = *(const u16x8_t*)(table + (size_t)r[u] * FDIM + c8);
        #pragma unroll
        for (int u = 0; u < U; u++) {
            a0[0] += bf2f(v[u][0]); a0[1] += bf2f(v[u][1]);
            a0[2] += bf2f(v[u][2]); a0[3] += bf2f(v[u][3]);
            a1[0] += bf2f(v[u][4]); a1[1] += bf2f(v[u][5]);
            a1[2] += bf2f(v[u][6]); a1[3] += bf2f(v[u][7]);
        }
    }
    if (i < i1) {
        u16x8_t v[U];
        #pragma unroll
        for (int u = 0; u < U; u++) {
            int row = i + 4 * u + sub;
            u16x8_t z = {};
            v[u] = z;
            if (row < i1)
                v[u] = *(const u16x8_t*)(table + (size_t)csr[row] * FDIM + c8);
        }
        #pragma unroll
        for (int u = 0; u < U; u++) {
            a0[0] += bf2f(v[u][0]); a0[1] += bf2f(v[u][1]);
            a0[2] += bf2f(v[u][2]); a0[3] += bf2f(v[u][3]);
            a1[0] += bf2f(v[u][4]); a1[1] += bf2f(v[u][5]);
            a1[2] += bf2f(v[u][6]); a1[3] += bf2f(v[u][7]);
        }
    }

    #pragma unroll
    for (int j = 0; j < 4; j++) {
        a0[j] += __shfl_xor(a0[j], 16, 64);
        a0[j] += __shfl_xor(a0[j], 32, 64);
        a1[j] += __shfl_xor(a1[j], 16, 64);
        a1[j] += __shfl_xor(a1[j], 32, 64);
    }

    if (sub < 2) {
        const int q = c8 + sub * 4;
        f32x4_t s = sub ? a1 : a0;
        if (agg_out)
            *(f32x4_t*)(agg_out + (size_t)seg * FDIM + q) = s;
        if (fin_out) {
            f32x4_t xv = *(const f32x4_t*)(x + (size_t)seg * FDIM + q);
            f32x4_t gg = *(const f32x4_t*)(g + q);
            f32x4_t bt = *(const f32x4_t*)(bb + q);
            f32x4_t mn = *(const f32x4_t*)(mm + q);
            f32x4_t vr = *(const f32x4_t*)(vv + q);
            f32x4_t o;
            #pragma unroll
            for (int j = 0; j < 4; j++)
                o[j] = sigmoidf_((xv[j] - mn[j]) * (gg[j] * rsqrtf(vr[j] + BN_EPS))
                                 + bt[j] + s[j]);
            *(f32x4_t*)(fin_out + (size_t)seg * FDIM + q) = o;
        }
    }
}

extern "C" void kernel_launch(void* const* d_in, const int* in_sizes, int n_in,
                              void* d_out, int out_size, void* d_ws, size_t ws_size,
                              hipStream_t stream)
{
    const float* x0       = (const float*)d_in[0];
    const float* x1       = (const float*)d_in[1];
    const int*   node_idx = (const int*)d_in[2];
    const int*   edge_idx = (const int*)d_in[3];
    const float* W_nh     = (const float*)d_in[4];
    const float* b_nh     = (const float*)d_in[5];
    const float* W_en     = (const float*)d_in[6];
    const float* b_en     = (const float*)d_in[7];
    const float* bn0g = (const float*)d_in[8];
    const float* bn0b = (const float*)d_in[9];
    const float* bn0m = (const float*)d_in[10];
    const float* bn0v = (const float*)d_in[11];
    const float* bn1g = (const float*)d_in[12];
    const float* bn1b = (const float*)d_in[13];
    const float* bn1m = (const float*)d_in[14];
    const float* bn1v = (const float*)d_in[15];

    float* ws = (float*)d_ws;
    float* B = ws;                                        // [20000,128] fp32
    unsigned short* Wnh_bf = (unsigned short*)(B + (size_t)NEDGES * FDIM);
    unsigned short* W1hi = Wnh_bf + FDIM * FDIM;
    unsigned short* W1lo = W1hi + FDIM * FDIM;
    unsigned short* W2hi = W1lo + FDIM * FDIM;
    unsigned short* W2lo = W2hi + FDIM * FDIM;
    unsigned short* A_bf = W2lo + FDIM * FDIM;            // [100000,128] bf16
    unsigned short* D_bf = A_bf + (size_t)NNODES * FDIM;  // [20000,128] bf16
    int* off_e = (int*)(D_bf + (size_t)NEDGES * FDIM);    // 20001 (pad 20004)
    int* off_n = off_e + 20004;                           // 100001 (pad 100004)
    unsigned* csr_e = (unsigned*)(off_n + 100004);        // 2M u32
    unsigned short* csr_n = (unsigned short*)(csr_e + NNZ_); // 2M u16
    unsigned* buck_e = (unsigned*)(csr_n + NNZ_);         // [NBUCK*CAP]
    unsigned* buck_n = buck_e + (size_t)NBUCK * CAP;      // [NBUCK*CAP]
    int* gcur_e = (int*)(buck_n + (size_t)NBUCK * CAP);   // 256
    int* gcur_n = gcur_e + NBUCK;                         // 256

    // 1) prep: zero gcur + weight conversions/splits
    prep_w<<<(3 * FDIM * FDIM + 255) / 256, 256, 0, stream>>>(
        W_nh, W_en, Wnh_bf, W1hi, W1lo, W2hi, W2lo, gcur_e);

    float* out0 = (float*)d_out;
    float* out1 = out0 + (size_t)NNODES * FDIM;

    // 2) fused: bucket_scatter (489 blocks) || gemm1 register-MFMA (782 blocks)
    const int nscatter = (NNZ_ + 4095) / 4096;             // 489
    const int ngemm1   = (NNODES + 127) / 128;             // 782
    scatter_gemm1<<<nscatter + ngemm1, 1024, 0, stream>>>(
        node_idx, edge_idx, buck_e, buck_n, gcur_e, gcur_n,
        x0, Wnh_bf, b_nh, A_bf, nscatter);

    // 3) bucket sort -> CSR both directions
    bucket_sort<<<2 * NBUCK, 256, 0, stream>>>(buck_e, buck_n, gcur_e, gcur_n,
                                               csr_e, csr_n, off_e, off_n);

    // 4) node -> hyperedge pull-aggregate (+ fused x1_out)
    seg_sum_fin_v2<unsigned, 8><<<(NEDGES + 3) / 4, 256, 0, stream>>>(
        A_bf, csr_e, off_e, x1, bn1g, bn1b, bn1m, bn1v, B, out1, NEDGES);

    // 5) GEMM2 register-MFMA (split-bf16, no LDS, 1250 blocks)
    gemm2_reg<<<(NEDGES / 32) * 2, 256, 0, stream>>>(
        x1, B, W1hi, W1lo, W2hi, W2lo, b_en, D_bf);

    // 6) hyperedge -> node pull-aggregate (+ fused x0_out)
    seg_sum_fin_v2<unsigned short, 4><<<(NNODES + 3) / 4, 256, 0, stream>>>(
        D_bf, csr_n, off_n, x0, bn0g, bn0b, bn0m, bn0v, nullptr, out0, NNODES);
}

// Round 9
// 393.079 us; speedup vs baseline: 1.0177x; 1.0017x over previous
//
#include <hip/hip_runtime.h>
#include <hip/hip_bf16.h>
#include <math.h>

#define NNODES 100000
#define NEDGES 20000
#define NNZ_   2000000
#define FDIM   128
#define BN_EPS 1e-5f

// ---- bucket-sort geometry (R1/R5 verified) ----
#define NBUCK 256
#define CAP   9216        // per-bucket capacity (mean ~7812, sigma ~88 -> +16 sigma)
#define BPB_E 79          // bins/bucket, edge dir
#define BPB_N 391         // bins/bucket, node dir
#define SH_E  17          // edge entry = (e<<17)|n
#define SH_N  15          // node entry = (n<<15)|e

typedef __attribute__((ext_vector_type(8))) short bf16x8_t;
typedef __attribute__((ext_vector_type(4))) float f32x4_t;
typedef __attribute__((ext_vector_type(8))) unsigned short u16x8_t;

__device__ __forceinline__ float sigmoidf_(float x) {
    return 1.0f / (1.0f + __expf(-x));
}
__device__ __forceinline__ float bf2f(unsigned short u) {
    return __uint_as_float(((unsigned)u) << 16);
}
__device__ __forceinline__ unsigned short f2bf(float f) {
    __hip_bfloat16 h = __float2bfloat16(f);   // RNE
    return *reinterpret_cast<unsigned short*>(&h);
}

// ---- prep (FIRST dispatch): zero gcur + bf16 W_nh + hi/lo split W_en ----
__global__ __launch_bounds__(256) void prep_w(
    const float* __restrict__ W_nh, const float* __restrict__ W_en,
    unsigned short* __restrict__ Wnh_bf,
    unsigned short* __restrict__ W1hi, unsigned short* __restrict__ W1lo,
    unsigned short* __restrict__ W2hi, unsigned short* __restrict__ W2lo,
    int* __restrict__ gcur)
{
    int idx = blockIdx.x * blockDim.x + threadIdx.x;
    if (idx < 2 * NBUCK) gcur[idx] = 0;
    if (idx < FDIM * FDIM) {
        Wnh_bf[idx] = f2bf(W_nh[idx]);
        return;
    }
    int j = idx - FDIM * FDIM;
    if (j >= 2 * FDIM * FDIM) return;
    int n = j >> 8, kk = j & 255;
    float w = W_en[n * 2 * FDIM + kk];
    unsigned short hi = f2bf(w);
    unsigned short lo = f2bf(w - bf2f(hi));
    int o = n * FDIM + (kk & 127);
    if (kk < FDIM) { W1hi[o] = hi; W1lo[o] = lo; }
    else           { W2hi[o] = hi; W2lo[o] = lo; }
}

// ---- GEMM1 register-resident (R8-verified tile body): 32x128/block, no LDS ----
__global__ __launch_bounds__(256) void gemm1_reg(
    const float* __restrict__ x0, const unsigned short* __restrict__ Wb,
    const float* __restrict__ bias, unsigned short* __restrict__ out)
{
    const int row0 = blockIdx.x * 32;
    const int tid  = threadIdx.x;
    const int wave  = tid >> 6;
    const int lane  = tid & 63;
    const int mhalf = wave & 1;
    const int nhalf = wave >> 1;
    const int lm    = lane & 15;
    const int quad  = lane >> 4;
    const float* ar = x0 + (size_t)(row0 + mhalf * 16 + lm) * FDIM;
    f32x4_t acc[4] = {};
    #pragma unroll
    for (int ks = 0; ks < 4; ks++) {
        const int ko = ks * 32 + quad * 8;
        float4 f0 = *(const float4*)(ar + ko);
        float4 f1 = *(const float4*)(ar + ko + 4);
        bf16x8_t a;
        a[0] = (short)f2bf(f0.x); a[1] = (short)f2bf(f0.y);
        a[2] = (short)f2bf(f0.z); a[3] = (short)f2bf(f0.w);
        a[4] = (short)f2bf(f1.x); a[5] = (short)f2bf(f1.y);
        a[6] = (short)f2bf(f1.z); a[7] = (short)f2bf(f1.w);
        #pragma unroll
        for (int nt = 0; nt < 4; nt++) {
            int n = nhalf * 64 + nt * 16 + lm;
            bf16x8_t b = *(const bf16x8_t*)(Wb + (size_t)n * FDIM + ko);
            acc[nt] = __builtin_amdgcn_mfma_f32_16x16x32_bf16(a, b, acc[nt], 0, 0, 0);
        }
    }
    const int mbase = row0 + mhalf * 16 + quad * 4;
    #pragma unroll
    for (int nt = 0; nt < 4; nt++) {
        int n = nhalf * 64 + nt * 16 + lm;
        float bv = bias[n];
        #pragma unroll
        for (int r2 = 0; r2 < 4; r2++) {
            out[(size_t)(mbase + r2) * FDIM + n] = f2bf(sigmoidf_(acc[nt][r2] + bv));
        }
    }
}

// ---- GEMM2 register-resident (R8 verified): no LDS, 6-pass hi/lo split ----
__device__ __forceinline__ void mfma_pass2(
    const bf16x8_t af[4], const unsigned short* __restrict__ W,
    int ncol, int lm, int quad, f32x4_t acc[2])
{
    #pragma unroll
    for (int ks = 0; ks < 4; ks++) {
        #pragma unroll
        for (int nt = 0; nt < 2; nt++) {
            int n = ncol + nt * 16 + lm;
            bf16x8_t b = *(const bf16x8_t*)(W + (size_t)n * FDIM + ks * 32 + quad * 8);
            acc[nt] = __builtin_amdgcn_mfma_f32_16x16x32_bf16(af[ks], b, acc[nt], 0, 0, 0);
        }
    }
}

__global__ __launch_bounds__(256) void gemm2_reg(
    const float* __restrict__ x1, const float* __restrict__ Bagg,
    const unsigned short* __restrict__ W1hi, const unsigned short* __restrict__ W1lo,
    const unsigned short* __restrict__ W2hi, const unsigned short* __restrict__ W2lo,
    const float* __restrict__ bias, unsigned short* __restrict__ out)
{
    const int row0 = (blockIdx.x >> 1) * 32;
    const int col0 = (blockIdx.x & 1) * 64;
    const int tid  = threadIdx.x;
    const int wave  = tid >> 6;
    const int lane  = tid & 63;
    const int mhalf = wave & 1;
    const int npair = wave >> 1;          // 0..1 -> 32-col slice
    const int lm    = lane & 15;
    const int quad  = lane >> 4;
    const int rowA  = row0 + mhalf * 16 + lm;
    const float* xr = x1   + (size_t)rowA * FDIM;
    const float* br = Bagg + (size_t)rowA * FDIM;

    bf16x8_t axh[4], axl[4], abh[4], abl[4];
    #pragma unroll
    for (int ks = 0; ks < 4; ks++) {
        const int ko = ks * 32 + quad * 8;
        float4 f0 = *(const float4*)(xr + ko);
        float4 f1 = *(const float4*)(xr + ko + 4);
        float4 g0 = *(const float4*)(br + ko);
        float4 g1 = *(const float4*)(br + ko + 4);
        float fx[8] = {f0.x, f0.y, f0.z, f0.w, f1.x, f1.y, f1.z, f1.w};
        float fb[8] = {g0.x, g0.y, g0.z, g0.w, g1.x, g1.y, g1.z, g1.w};
        #pragma unroll
        for (int j = 0; j < 8; j++) {
            unsigned short h = f2bf(fx[j]);
            axh[ks][j] = (short)h;
            axl[ks][j] = (short)f2bf(fx[j] - bf2f(h));
            unsigned short hb = f2bf(fb[j]);
            abh[ks][j] = (short)hb;
            abl[ks][j] = (short)f2bf(fb[j] - bf2f(hb));
        }
    }

    f32x4_t acc[2] = {};
    const int ncol = col0 + npair * 32;
    mfma_pass2(axh, W1hi, ncol, lm, quad, acc);
    mfma_pass2(axl, W1hi, ncol, lm, quad, acc);
    mfma_pass2(axh, W1lo, ncol, lm, quad, acc);
    mfma_pass2(abh, W2hi, ncol, lm, quad, acc);
    mfma_pass2(abl, W2hi, ncol, lm, quad, acc);
    mfma_pass2(abh, W2lo, ncol, lm, quad, acc);

    const int mbase = row0 + mhalf * 16 + quad * 4;
    #pragma unroll
    for (int nt = 0; nt < 2; nt++) {
        int n = ncol + nt * 16 + lm;
        float bv = bias[n];
        #pragma unroll
        for (int r2 = 0; r2 < 4; r2++) {
            out[(size_t)(mbase + r2) * FDIM + n] = f2bf(sigmoidf_(acc[nt][r2] + bv));
        }
    }
}

// ---- Pass A: coarse bucket partition, standalone (R5 verified) ----
__global__ __launch_bounds__(1024) void bucket_scatter(
    const int* __restrict__ ni, const int* __restrict__ ei,
    unsigned* __restrict__ buck_e, unsigned* __restrict__ buck_n,
    int* __restrict__ gcur_e, int* __restrict__ gcur_n)
{
    __shared__ int lh_e[NBUCK], lh_n[NBUCK], lb_e[NBUCK], lb_n[NBUCK];
    const int t = threadIdx.x;
    if (t < NBUCK) { lh_e[t] = 0; lh_n[t] = 0; }
    __syncthreads();
    unsigned ent_e[4], ent_n[4];
    int be[4], bn[4], re[4], rn[4];
    const int base = blockIdx.x * 4096;
    #pragma unroll
    for (int j = 0; j < 4; j++) {
        int i = base + j * 1024 + t;
        if (i < NNZ_) {
            unsigned n = (unsigned)ni[i], e = (unsigned)ei[i];
            ent_e[j] = (e << SH_E) | n;  be[j] = (int)(e / BPB_E);
            ent_n[j] = (n << SH_N) | e;  bn[j] = (int)(n / BPB_N);
            re[j] = atomicAdd(&lh_e[be[j]], 1);
            rn[j] = atomicAdd(&lh_n[bn[j]], 1);
        } else { be[j] = -1; }
    }
    __syncthreads();
    if (t < NBUCK) {
        lb_e[t] = t * CAP + atomicAdd(&gcur_e[t], lh_e[t]);
        lb_n[t] = t * CAP + atomicAdd(&gcur_n[t], lh_n[t]);
    }
    __syncthreads();
    #pragma unroll
    for (int j = 0; j < 4; j++) {
        if (be[j] >= 0) {
            buck_e[(size_t)lb_e[be[j]] + re[j]] = ent_e[j];
            buck_n[(size_t)lb_n[bn[j]] + rn[j]] = ent_n[j];
        }
    }
}

// ---- Pass B: sort one bucket into its compact region (R1/R5 verified) ----
template<int BPB, int SH, unsigned MASK, int NBINS, typename OUT>
__device__ __forceinline__ void sort_bucket(
    const unsigned* __restrict__ region, int cnt, int gbase, int b0,
    OUT* __restrict__ csr, int* __restrict__ off)
{
    __shared__ unsigned lh[512];
    __shared__ unsigned lw[4];
    const int t = threadIdx.x;
    lh[t] = 0; lh[t + 256] = 0;
    __syncthreads();
    for (int i = t; i < cnt; i += 256) {
        int bin = (int)(region[i] >> SH) - b0;
        atomicAdd(&lh[bin], 1u);
    }
    __syncthreads();
    unsigned h0 = lh[2 * t], h1 = lh[2 * t + 1];
    unsigned s = h0 + h1, inc = s;
    const int lane = t & 63;
    #pragma unroll
    for (int d = 1; d <= 32; d <<= 1) {
        unsigned v = (unsigned)__shfl_up((int)inc, d, 64);
        if (lane >= d) inc += v;
    }
    if (lane == 63) lw[t >> 6] = inc;
    __syncthreads();
    unsigned pre = 0;
    #pragma unroll
    for (int w = 0; w < 4; w++) if (w < (t >> 6)) pre += lw[w];
    unsigned excl = pre + inc - s;
    unsigned c0 = (unsigned)gbase + excl;
    unsigned c1 = c0 + h0;
    lh[2 * t] = c0; lh[2 * t + 1] = c1;
    int i0 = 2 * t, i1 = 2 * t + 1;
    if (i0 <= BPB && b0 + i0 <= NBINS) off[b0 + i0] = (int)c0;
    if (i1 <= BPB && b0 + i1 <= NBINS) off[b0 + i1] = (int)c1;
    __syncthreads();
    for (int i = t; i < cnt; i += 256) {
        unsigned ent = region[i];
        int bin = (int)(ent >> SH) - b0;
        unsigned pos = atomicAdd(&lh[bin], 1u);
        csr[pos] = (OUT)(ent & MASK);
    }
}

__global__ __launch_bounds__(256) void bucket_sort(
    const unsigned* __restrict__ buck_e, const unsigned* __restrict__ buck_n,
    const int* __restrict__ gcur_e, const int* __restrict__ gcur_n,
    unsigned* __restrict__ csr_e, unsigned short* __restrict__ csr_n,
    int* __restrict__ off_e, int* __restrict__ off_n)
{
    const int b = blockIdx.x & 255;
    const int* gc = (blockIdx.x < 256) ? gcur_e : gcur_n;
    __shared__ int ws4[4];
    const int t = threadIdx.x;
    int v = (t < b) ? gc[t] : 0;
    #pragma unroll
    for (int d = 32; d > 0; d >>= 1) v += __shfl_down(v, d, 64);
    if ((t & 63) == 0) ws4[t >> 6] = v;
    __syncthreads();
    const int gbase = ws4[0] + ws4[1] + ws4[2] + ws4[3];
    const int cnt = gc[b];
    __syncthreads();
    if (blockIdx.x < 256)
        sort_bucket<BPB_E, SH_E, 0x1FFFFu, NEDGES, unsigned>(
            buck_e + (size_t)b * CAP, cnt, gbase, b * BPB_E, csr_e, off_e);
    else
        sort_bucket<BPB_N, SH_N, 0x7FFFu, NNODES, unsigned short>(
            buck_n + (size_t)b * CAP, cnt, gbase, b * BPB_N, csr_n, off_n);
}

// ---- segmented sum v2: one wave per segment, 16B gathers, deep ILP (R5) ----
template<typename IDX, int U>
__global__ __launch_bounds__(256) void seg_sum_fin_v2(
    const unsigned short* __restrict__ table, const IDX* __restrict__ csr,
    const int* __restrict__ off, const float* __restrict__ x,
    const float* __restrict__ g, const float* __restrict__ bb,
    const float* __restrict__ mm, const float* __restrict__ vv,
    float* __restrict__ agg_out, float* __restrict__ fin_out, int nseg)
{
    const int seg = blockIdx.x * 4 + (threadIdx.x >> 6);
    if (seg >= nseg) return;
    const int lane = threadIdx.x & 63;
    const int c    = lane & 15;
    const int sub  = lane >> 4;
    const int c8   = c * 8;

    const int i0 = off[seg], i1 = off[seg + 1];
    f32x4_t a0 = {}, a1 = {};

    int i = i0;
    for (; i + 4 * U <= i1; i += 4 * U) {
        int r[U];
        u16x8_t v[U];
        #pragma unroll
        for (int u = 0; u < U; u++) r[u] = (int)csr[i + 4 * u + sub];
        #pragma unroll
        for (int u = 0; u < U; u++)
            v[u] = *(const u16x8_t*)(table + (size_t)r[u] * FDIM + c8);
        #pragma unroll
        for (int u = 0; u < U; u++) {
            a0[0] += bf2f(v[u][0]); a0[1] += bf2f(v[u][1]);
            a0[2] += bf2f(v[u][2]); a0[3] += bf2f(v[u][3]);
            a1[0] += bf2f(v[u][4]); a1[1] += bf2f(v[u][5]);
            a1[2] += bf2f(v[u][6]); a1[3] += bf2f(v[u][7]);
        }
    }
    if (i < i1) {
        u16x8_t v[U];
        #pragma unroll
        for (int u = 0; u < U; u++) {
            int row = i + 4 * u + sub;
            u16x8_t z = {};
            v[u] = z;
            if (row < i1)
                v[u] = *(const u16x8_t*)(table + (size_t)csr[row] * FDIM + c8);
        }
        #pragma unroll
        for (int u = 0; u < U; u++) {
            a0[0] += bf2f(v[u][0]); a0[1] += bf2f(v[u][1]);
            a0[2] += bf2f(v[u][2]); a0[3] += bf2f(v[u][3]);
            a1[0] += bf2f(v[u][4]); a1[1] += bf2f(v[u][5]);
            a1[2] += bf2f(v[u][6]); a1[3] += bf2f(v[u][7]);
        }
    }

    #pragma unroll
    for (int j = 0; j < 4; j++) {
        a0[j] += __shfl_xor(a0[j], 16, 64);
        a0[j] += __shfl_xor(a0[j], 32, 64);
        a1[j] += __shfl_xor(a1[j], 16, 64);
        a1[j] += __shfl_xor(a1[j], 32, 64);
    }

    if (sub < 2) {
        const int q = c8 + sub * 4;
        f32x4_t s = sub ? a1 : a0;
        if (agg_out)
            *(f32x4_t*)(agg_out + (size_t)seg * FDIM + q) = s;
        if (fin_out) {
            f32x4_t xv = *(const f32x4_t*)(x + (size_t)seg * FDIM + q);
            f32x4_t gg = *(const f32x4_t*)(g + q);
            f32x4_t bt = *(const f32x4_t*)(bb + q);
            f32x4_t mn = *(const f32x4_t*)(mm + q);
            f32x4_t vr = *(const f32x4_t*)(vv + q);
            f32x4_t o;
            #pragma unroll
            for (int j = 0; j < 4; j++)
                o[j] = sigmoidf_((xv[j] - mn[j]) * (gg[j] * rsqrtf(vr[j] + BN_EPS))
                                 + bt[j] + s[j]);
            *(f32x4_t*)(fin_out + (size_t)seg * FDIM + q) = o;
        }
    }
}

extern "C" void kernel_launch(void* const* d_in, const int* in_sizes, int n_in,
                              void* d_out, int out_size, void* d_ws, size_t ws_size,
                              hipStream_t stream)
{
    const float* x0       = (const float*)d_in[0];
    const float* x1       = (const float*)d_in[1];
    const int*   node_idx = (const int*)d_in[2];
    const int*   edge_idx = (const int*)d_in[3];
    const float* W_nh     = (const float*)d_in[4];
    const float* b_nh     = (const float*)d_in[5];
    const float* W_en     = (const float*)d_in[6];
    const float* b_en     = (const float*)d_in[7];
    const float* bn0g = (const float*)d_in[8];
    const float* bn0b = (const float*)d_in[9];
    const float* bn0m = (const float*)d_in[10];
    const float* bn0v = (const float*)d_in[11];
    const float* bn1g = (const float*)d_in[12];
    const float* bn1b = (const float*)d_in[13];
    const float* bn1m = (const float*)d_in[14];
    const float* bn1v = (const float*)d_in[15];

    float* ws = (float*)d_ws;
    float* B = ws;                                        // [20000,128] fp32
    unsigned short* Wnh_bf = (unsigned short*)(B + (size_t)NEDGES * FDIM);
    unsigned short* W1hi = Wnh_bf + FDIM * FDIM;
    unsigned short* W1lo = W1hi + FDIM * FDIM;
    unsigned short* W2hi = W1lo + FDIM * FDIM;
    unsigned short* W2lo = W2hi + FDIM * FDIM;
    unsigned short* A_bf = W2lo + FDIM * FDIM;            // [100000,128] bf16
    unsigned short* D_bf = A_bf + (size_t)NNODES * FDIM;  // [20000,128] bf16
    int* off_e = (int*)(D_bf + (size_t)NEDGES * FDIM);    // 20001 (pad 20004)
    int* off_n = off_e + 20004;                           // 100001 (pad 100004)
    unsigned* csr_e = (unsigned*)(off_n + 100004);        // 2M u32
    unsigned short* csr_n = (unsigned short*)(csr_e + NNZ_); // 2M u16
    unsigned* buck_e = (unsigned*)(csr_n + NNZ_);         // [NBUCK*CAP]
    unsigned* buck_n = buck_e + (size_t)NBUCK * CAP;      // [NBUCK*CAP]
    int* gcur_e = (int*)(buck_n + (size_t)NBUCK * CAP);   // 256
    int* gcur_n = gcur_e + NBUCK;                         // 256

    // 1) prep: zero gcur + weight conversions/splits
    prep_w<<<(3 * FDIM * FDIM + 255) / 256, 256, 0, stream>>>(
        W_nh, W_en, Wnh_bf, W1hi, W1lo, W2hi, W2lo, gcur_e);

    float* out0 = (float*)d_out;
    float* out1 = out0 + (size_t)NNODES * FDIM;

    // 2) CSR build: scatter then sort (standalone, verified)
    bucket_scatter<<<(NNZ_ + 4095) / 4096, 1024, 0, stream>>>(
        node_idx, edge_idx, buck_e, buck_n, gcur_e, gcur_n);
    bucket_sort<<<2 * NBUCK, 256, 0, stream>>>(buck_e, buck_n, gcur_e, gcur_n,
                                               csr_e, csr_n, off_e, off_n);

    // 3) GEMM1 register-MFMA (no LDS, 3125 blocks)
    gemm1_reg<<<NNODES / 32, 256, 0, stream>>>(x0, Wnh_bf, b_nh, A_bf);

    // 4) node -> hyperedge pull-aggregate (+ fused x1_out)
    seg_sum_fin_v2<unsigned, 8><<<(NEDGES + 3) / 4, 256, 0, stream>>>(
        A_bf, csr_e, off_e, x1, bn1g, bn1b, bn1m, bn1v, B, out1, NEDGES);

    // 5) GEMM2 register-MFMA (split-bf16, no LDS, 1250 blocks)
    gemm2_reg<<<(NEDGES / 32) * 2, 256, 0, stream>>>(
        x1, B, W1hi, W1lo, W2hi, W2lo, b_en, D_bf);

    // 6) hyperedge -> node pull-aggregate (+ fused x0_out)
    seg_sum_fin_v2<unsigned short, 4><<<(NNODES + 3) / 4, 256, 0, stream>>>(
        D_bf, csr_n, off_n, x0, bn0g, bn0b, bn0m, bn0v, nullptr, out0, NNODES);
}

// Round 10
// 391.941 us; speedup vs baseline: 1.0207x; 1.0029x over previous
//
#include <hip/hip_runtime.h>
#include <hip/hip_bf16.h>
#include <math.h>

#define NNODES 100000
#define NEDGES 20000
#define NNZ_   2000000
#define FDIM   128
#define BN_EPS 1e-5f

// ---- bucket-sort geometry (R1/R5 verified) ----
#define NBUCK 256
#define CAP   9216        // per-bucket capacity (mean ~7812, sigma ~88 -> +16 sigma)
#define BPB_E 79          // bins/bucket, edge dir
#define BPB_N 391         // bins/bucket, node dir
#define SH_E  17          // edge entry = (e<<17)|n
#define SH_N  15          // node entry = (n<<15)|e

typedef __attribute__((ext_vector_type(8))) short bf16x8_t;
typedef __attribute__((ext_vector_type(4))) float f32x4_t;
typedef __attribute__((ext_vector_type(8))) unsigned short u16x8_t;

__device__ __forceinline__ float sigmoidf_(float x) {
    return 1.0f / (1.0f + __expf(-x));
}
__device__ __forceinline__ float bf2f(unsigned short u) {
    return __uint_as_float(((unsigned)u) << 16);
}
__device__ __forceinline__ unsigned short f2bf(float f) {
    __hip_bfloat16 h = __float2bfloat16(f);   // RNE
    return *reinterpret_cast<unsigned short*>(&h);
}

// ---- prep (FIRST dispatch): zero gcur + bf16 W_nh + hi/lo split W_en ----
__global__ __launch_bounds__(256) void prep_w(
    const float* __restrict__ W_nh, const float* __restrict__ W_en,
    unsigned short* __restrict__ Wnh_bf,
    unsigned short* __restrict__ W1hi, unsigned short* __restrict__ W1lo,
    unsigned short* __restrict__ W2hi, unsigned short* __restrict__ W2lo,
    int* __restrict__ gcur)
{
    int idx = blockIdx.x * blockDim.x + threadIdx.x;
    if (idx < 2 * NBUCK) gcur[idx] = 0;
    if (idx < FDIM * FDIM) {
        Wnh_bf[idx] = f2bf(W_nh[idx]);
        return;
    }
    int j = idx - FDIM * FDIM;
    if (j >= 2 * FDIM * FDIM) return;
    int n = j >> 8, kk = j & 255;
    float w = W_en[n * 2 * FDIM + kk];
    unsigned short hi = f2bf(w);
    unsigned short lo = f2bf(w - bf2f(hi));
    int o = n * FDIM + (kk & 127);
    if (kk < FDIM) { W1hi[o] = hi; W1lo[o] = lo; }
    else           { W2hi[o] = hi; W2lo[o] = lo; }
}

// ---- GEMM1 via MFMA (R5-verified LDS version) ----
__global__ __launch_bounds__(256) void gemm1_mfma(
    const float* __restrict__ x0, const unsigned short* __restrict__ Wb,
    const float* __restrict__ bias, unsigned short* __restrict__ out)
{
    __shared__ unsigned short As[32][FDIM + 8];
    const int tid  = threadIdx.x;
    const int row0 = blockIdx.x * 32;
    {
        int r = tid >> 3, c0 = (tid & 7) * 16;
        const float* src = x0 + (size_t)(row0 + r) * FDIM + c0;
        unsigned short* dst = &As[r][c0];
        #pragma unroll
        for (int i = 0; i < 4; i++) {
            float4 v = *(const float4*)(src + i * 4);
            dst[i * 4 + 0] = f2bf(v.x);
            dst[i * 4 + 1] = f2bf(v.y);
            dst[i * 4 + 2] = f2bf(v.z);
            dst[i * 4 + 3] = f2bf(v.w);
        }
    }
    __syncthreads();
    const int wave  = tid >> 6;
    const int lane  = tid & 63;
    const int mhalf = wave & 1;
    const int nhalf = wave >> 1;
    const int lm    = lane & 15;
    const int quad  = lane >> 4;
    f32x4_t acc[4] = {};
    #pragma unroll
    for (int ks = 0; ks < 4; ks++) {
        bf16x8_t a = *(const bf16x8_t*)&As[mhalf * 16 + lm][ks * 32 + quad * 8];
        #pragma unroll
        for (int nt = 0; nt < 4; nt++) {
            int n = nhalf * 64 + nt * 16 + lm;
            bf16x8_t b = *(const bf16x8_t*)(Wb + (size_t)n * FDIM + ks * 32 + quad * 8);
            acc[nt] = __builtin_amdgcn_mfma_f32_16x16x32_bf16(a, b, acc[nt], 0, 0, 0);
        }
    }
    const int mbase = row0 + mhalf * 16 + quad * 4;
    #pragma unroll
    for (int nt = 0; nt < 4; nt++) {
        int n = nhalf * 64 + nt * 16 + lm;
        float bv = bias[n];
        #pragma unroll
        for (int r2 = 0; r2 < 4; r2++) {
            out[(size_t)(mbase + r2) * FDIM + n] = f2bf(sigmoidf_(acc[nt][r2] + bv));
        }
    }
}

// ---- GEMM2 register-resident (R8/R9 verified): no LDS, 6-pass hi/lo split ----
__device__ __forceinline__ void mfma_pass2(
    const bf16x8_t af[4], const unsigned short* __restrict__ W,
    int ncol, int lm, int quad, f32x4_t acc[2])
{
    #pragma unroll
    for (int ks = 0; ks < 4; ks++) {
        #pragma unroll
        for (int nt = 0; nt < 2; nt++) {
            int n = ncol + nt * 16 + lm;
            bf16x8_t b = *(const bf16x8_t*)(W + (size_t)n * FDIM + ks * 32 + quad * 8);
            acc[nt] = __builtin_amdgcn_mfma_f32_16x16x32_bf16(af[ks], b, acc[nt], 0, 0, 0);
        }
    }
}

__global__ __launch_bounds__(256) void gemm2_reg(
    const float* __restrict__ x1, const float* __restrict__ Bagg,
    const unsigned short* __restrict__ W1hi, const unsigned short* __restrict__ W1lo,
    const unsigned short* __restrict__ W2hi, const unsigned short* __restrict__ W2lo,
    const float* __restrict__ bias, unsigned short* __restrict__ out)
{
    const int row0 = (blockIdx.x >> 1) * 32;
    const int col0 = (blockIdx.x & 1) * 64;
    const int tid  = threadIdx.x;
    const int wave  = tid >> 6;
    const int lane  = tid & 63;
    const int mhalf = wave & 1;
    const int npair = wave >> 1;          // 0..1 -> 32-col slice
    const int lm    = lane & 15;
    const int quad  = lane >> 4;
    const int rowA  = row0 + mhalf * 16 + lm;
    const float* xr = x1   + (size_t)rowA * FDIM;
    const float* br = Bagg + (size_t)rowA * FDIM;

    bf16x8_t axh[4], axl[4], abh[4], abl[4];
    #pragma unroll
    for (int ks = 0; ks < 4; ks++) {
        const int ko = ks * 32 + quad * 8;
        float4 f0 = *(const float4*)(xr + ko);
        float4 f1 = *(const float4*)(xr + ko + 4);
        float4 g0 = *(const float4*)(br + ko);
        float4 g1 = *(const float4*)(br + ko + 4);
        float fx[8] = {f0.x, f0.y, f0.z, f0.w, f1.x, f1.y, f1.z, f1.w};
        float fb[8] = {g0.x, g0.y, g0.z, g0.w, g1.x, g1.y, g1.z, g1.w};
        #pragma unroll
        for (int j = 0; j < 8; j++) {
            unsigned short h = f2bf(fx[j]);
            axh[ks][j] = (short)h;
            axl[ks][j] = (short)f2bf(fx[j] - bf2f(h));
            unsigned short hb = f2bf(fb[j]);
            abh[ks][j] = (short)hb;
            abl[ks][j] = (short)f2bf(fb[j] - bf2f(hb));
        }
    }

    f32x4_t acc[2] = {};
    const int ncol = col0 + npair * 32;
    mfma_pass2(axh, W1hi, ncol, lm, quad, acc);
    mfma_pass2(axl, W1hi, ncol, lm, quad, acc);
    mfma_pass2(axh, W1lo, ncol, lm, quad, acc);
    mfma_pass2(abh, W2hi, ncol, lm, quad, acc);
    mfma_pass2(abl, W2hi, ncol, lm, quad, acc);
    mfma_pass2(abh, W2lo, ncol, lm, quad, acc);

    const int mbase = row0 + mhalf * 16 + quad * 4;
    #pragma unroll
    for (int nt = 0; nt < 2; nt++) {
        int n = ncol + nt * 16 + lm;
        float bv = bias[n];
        #pragma unroll
        for (int r2 = 0; r2 < 4; r2++) {
            out[(size_t)(mbase + r2) * FDIM + n] = f2bf(sigmoidf_(acc[nt][r2] + bv));
        }
    }
}

// ---- Pass A: coarse bucket partition (R5 verified) ----
__global__ __launch_bounds__(1024) void bucket_scatter(
    const int* __restrict__ ni, const int* __restrict__ ei,
    unsigned* __restrict__ buck_e, unsigned* __restrict__ buck_n,
    int* __restrict__ gcur_e, int* __restrict__ gcur_n)
{
    __shared__ int lh_e[NBUCK], lh_n[NBUCK], lb_e[NBUCK], lb_n[NBUCK];
    const int t = threadIdx.x;
    if (t < NBUCK) { lh_e[t] = 0; lh_n[t] = 0; }
    __syncthreads();
    unsigned ent_e[4], ent_n[4];
    int be[4], bn[4], re[4], rn[4];
    const int base = blockIdx.x * 4096;
    #pragma unroll
    for (int j = 0; j < 4; j++) {
        int i = base + j * 1024 + t;
        if (i < NNZ_) {
            unsigned n = (unsigned)ni[i], e = (unsigned)ei[i];
            ent_e[j] = (e << SH_E) | n;  be[j] = (int)(e / BPB_E);
            ent_n[j] = (n << SH_N) | e;  bn[j] = (int)(n / BPB_N);
            re[j] = atomicAdd(&lh_e[be[j]], 1);
            rn[j] = atomicAdd(&lh_n[bn[j]], 1);
        } else { be[j] = -1; }
    }
    __syncthreads();
    if (t < NBUCK) {
        lb_e[t] = t * CAP + atomicAdd(&gcur_e[t], lh_e[t]);
        lb_n[t] = t * CAP + atomicAdd(&gcur_n[t], lh_n[t]);
    }
    __syncthreads();
    #pragma unroll
    for (int j = 0; j < 4; j++) {
        if (be[j] >= 0) {
            buck_e[(size_t)lb_e[be[j]] + re[j]] = ent_e[j];
            buck_n[(size_t)lb_n[bn[j]] + rn[j]] = ent_n[j];
        }
    }
}

// ---- Pass B: sort one bucket; csr stores PREMULTIPLIED (idx<<7) offsets ----
template<int BPB, int SH, unsigned MASK, int NBINS>
__device__ __forceinline__ void sort_bucket(
    const unsigned* __restrict__ region, int cnt, int gbase, int b0,
    unsigned* __restrict__ csr, int* __restrict__ off)
{
    __shared__ unsigned lh[512];
    __shared__ unsigned lw[4];
    const int t = threadIdx.x;
    lh[t] = 0; lh[t + 256] = 0;
    __syncthreads();
    for (int i = t; i < cnt; i += 256) {
        int bin = (int)(region[i] >> SH) - b0;
        atomicAdd(&lh[bin], 1u);
    }
    __syncthreads();
    unsigned h0 = lh[2 * t], h1 = lh[2 * t + 1];
    unsigned s = h0 + h1, inc = s;
    const int lane = t & 63;
    #pragma unroll
    for (int d = 1; d <= 32; d <<= 1) {
        unsigned v = (unsigned)__shfl_up((int)inc, d, 64);
        if (lane >= d) inc += v;
    }
    if (lane == 63) lw[t >> 6] = inc;
    __syncthreads();
    unsigned pre = 0;
    #pragma unroll
    for (int w = 0; w < 4; w++) if (w < (t >> 6)) pre += lw[w];
    unsigned excl = pre + inc - s;
    unsigned c0 = (unsigned)gbase + excl;
    unsigned c1 = c0 + h0;
    lh[2 * t] = c0; lh[2 * t + 1] = c1;
    int i0 = 2 * t, i1 = 2 * t + 1;
    if (i0 <= BPB && b0 + i0 <= NBINS) off[b0 + i0] = (int)c0;
    if (i1 <= BPB && b0 + i1 <= NBINS) off[b0 + i1] = (int)c1;
    __syncthreads();
    for (int i = t; i < cnt; i += 256) {
        unsigned ent = region[i];
        int bin = (int)(ent >> SH) - b0;
        unsigned pos = atomicAdd(&lh[bin], 1u);
        csr[pos] = (ent & MASK) << 7;   // element offset = idx * FDIM
    }
}

__global__ __launch_bounds__(256) void bucket_sort(
    const unsigned* __restrict__ buck_e, const unsigned* __restrict__ buck_n,
    const int* __restrict__ gcur_e, const int* __restrict__ gcur_n,
    unsigned* __restrict__ csr_e, unsigned* __restrict__ csr_n,
    int* __restrict__ off_e, int* __restrict__ off_n)
{
    const int b = blockIdx.x & 255;
    const int* gc = (blockIdx.x < 256) ? gcur_e : gcur_n;
    __shared__ int ws4[4];
    const int t = threadIdx.x;
    int v = (t < b) ? gc[t] : 0;
    #pragma unroll
    for (int d = 32; d > 0; d >>= 1) v += __shfl_down(v, d, 64);
    if ((t & 63) == 0) ws4[t >> 6] = v;
    __syncthreads();
    const int gbase = ws4[0] + ws4[1] + ws4[2] + ws4[3];
    const int cnt = gc[b];
    __syncthreads();
    if (blockIdx.x < 256)
        sort_bucket<BPB_E, SH_E, 0x1FFFFu, NEDGES>(
            buck_e + (size_t)b * CAP, cnt, gbase, b * BPB_E, csr_e, off_e);
    else
        sort_bucket<BPB_N, SH_N, 0x7FFFu, NNODES>(
            buck_n + (size_t)b * CAP, cnt, gbase, b * BPB_N, csr_n, off_n);
}

// ---- segmented sum v2: one wave/segment; csr holds premultiplied offsets ----
template<int U>
__global__ __launch_bounds__(256) void seg_sum_fin_v2(
    const unsigned short* __restrict__ table, const unsigned* __restrict__ csr,
    const int* __restrict__ off, const float* __restrict__ x,
    const float* __restrict__ g, const float* __restrict__ bb,
    const float* __restrict__ mm, const float* __restrict__ vv,
    float* __restrict__ agg_out, float* __restrict__ fin_out, int nseg)
{
    const int seg = blockIdx.x * 4 + (threadIdx.x >> 6);
    if (seg >= nseg) return;
    const int lane = threadIdx.x & 63;
    const int c    = lane & 15;
    const int sub  = lane >> 4;
    const int c8   = c * 8;

    const int i0 = off[seg], i1 = off[seg + 1];
    f32x4_t a0 = {}, a1 = {};

    int i = i0;
    for (; i + 4 * U <= i1; i += 4 * U) {
        unsigned r[U];
        u16x8_t v[U];
        #pragma unroll
        for (int u = 0; u < U; u++) r[u] = csr[i + 4 * u + sub];
        #pragma unroll
        for (int u = 0; u < U; u++)
            v[u] = *(const u16x8_t*)(table + (size_t)r[u] + c8);
        #pragma unroll
        for (int u = 0; u < U; u++) {
            a0[0] += bf2f(v[u][0]); a0[1] += bf2f(v[u][1]);
            a0[2] += bf2f(v[u][2]); a0[3] += bf2f(v[u][3]);
            a1[0] += bf2f(v[u][4]); a1[1] += bf2f(v[u][5]);
            a1[2] += bf2f(v[u][6]); a1[3] += bf2f(v[u][7]);
        }
    }
    if (i < i1) {
        u16x8_t v[U];
        #pragma unroll
        for (int u = 0; u < U; u++) {
            int row = i + 4 * u + sub;
            u16x8_t z = {};
            v[u] = z;
            if (row < i1)
                v[u] = *(const u16x8_t*)(table + (size_t)csr[row] + c8);
        }
        #pragma unroll
        for (int u = 0; u < U; u++) {
            a0[0] += bf2f(v[u][0]); a0[1] += bf2f(v[u][1]);
            a0[2] += bf2f(v[u][2]); a0[3] += bf2f(v[u][3]);
            a1[0] += bf2f(v[u][4]); a1[1] += bf2f(v[u][5]);
            a1[2] += bf2f(v[u][6]); a1[3] += bf2f(v[u][7]);
        }
    }

    #pragma unroll
    for (int j = 0; j < 4; j++) {
        a0[j] += __shfl_xor(a0[j], 16, 64);
        a0[j] += __shfl_xor(a0[j], 32, 64);
        a1[j] += __shfl_xor(a1[j], 16, 64);
        a1[j] += __shfl_xor(a1[j], 32, 64);
    }

    if (sub < 2) {
        const int q = c8 + sub * 4;
        f32x4_t s = sub ? a1 : a0;
        if (agg_out)
            *(f32x4_t*)(agg_out + (size_t)seg * FDIM + q) = s;
        if (fin_out) {
            f32x4_t xv = *(const f32x4_t*)(x + (size_t)seg * FDIM + q);
            f32x4_t gg = *(const f32x4_t*)(g + q);
            f32x4_t bt = *(const f32x4_t*)(bb + q);
            f32x4_t mn = *(const f32x4_t*)(mm + q);
            f32x4_t vr = *(const f32x4_t*)(vv + q);
            f32x4_t o;
            #pragma unroll
            for (int j = 0; j < 4; j++)
                o[j] = sigmoidf_((xv[j] - mn[j]) * (gg[j] * rsqrtf(vr[j] + BN_EPS))
                                 + bt[j] + s[j]);
            *(f32x4_t*)(fin_out + (size_t)seg * FDIM + q) = o;
        }
    }
}

extern "C" void kernel_launch(void* const* d_in, const int* in_sizes, int n_in,
                              void* d_out, int out_size, void* d_ws, size_t ws_size,
                              hipStream_t stream)
{
    const float* x0       = (const float*)d_in[0];
    const float* x1       = (const float*)d_in[1];
    const int*   node_idx = (const int*)d_in[2];
    const int*   edge_idx = (const int*)d_in[3];
    const float* W_nh     = (const float*)d_in[4];
    const float* b_nh     = (const float*)d_in[5];
    const float* W_en     = (const float*)d_in[6];
    const float* b_en     = (const float*)d_in[7];
    const float* bn0g = (const float*)d_in[8];
    const float* bn0b = (const float*)d_in[9];
    const float* bn0m = (const float*)d_in[10];
    const float* bn0v = (const float*)d_in[11];
    const float* bn1g = (const float*)d_in[12];
    const float* bn1b = (const float*)d_in[13];
    const float* bn1m = (const float*)d_in[14];
    const float* bn1v = (const float*)d_in[15];

    float* ws = (float*)d_ws;
    float* B = ws;                                        // [20000,128] fp32
    unsigned short* Wnh_bf = (unsigned short*)(B + (size_t)NEDGES * FDIM);
    unsigned short* W1hi = Wnh_bf + FDIM * FDIM;
    unsigned short* W1lo = W1hi + FDIM * FDIM;
    unsigned short* W2hi = W1lo + FDIM * FDIM;
    unsigned short* W2lo = W2hi + FDIM * FDIM;
    unsigned short* A_bf = W2lo + FDIM * FDIM;            // [100000,128] bf16
    unsigned short* D_bf = A_bf + (size_t)NNODES * FDIM;  // [20000,128] bf16
    int* off_e = (int*)(D_bf + (size_t)NEDGES * FDIM);    // 20001 (pad 20004)
    int* off_n = off_e + 20004;                           // 100001 (pad 100004)
    unsigned* csr_e = (unsigned*)(off_n + 100004);        // 2M u32 (premul offsets)
    unsigned* csr_n = csr_e + NNZ_;                       // 2M u32 (premul offsets)
    unsigned* buck_e = csr_n + NNZ_;                      // [NBUCK*CAP]
    unsigned* buck_n = buck_e + (size_t)NBUCK * CAP;      // [NBUCK*CAP]
    int* gcur_e = (int*)(buck_n + (size_t)NBUCK * CAP);   // 256
    int* gcur_n = gcur_e + NBUCK;                         // 256

    // 1) prep: zero gcur + weight conversions/splits
    prep_w<<<(3 * FDIM * FDIM + 255) / 256, 256, 0, stream>>>(
        W_nh, W_en, Wnh_bf, W1hi, W1lo, W2hi, W2lo, gcur_e);

    float* out0 = (float*)d_out;
    float* out1 = out0 + (size_t)NNODES * FDIM;

    // 2) CSR build: scatter then sort (premultiplied csr offsets)
    bucket_scatter<<<(NNZ_ + 4095) / 4096, 1024, 0, stream>>>(
        node_idx, edge_idx, buck_e, buck_n, gcur_e, gcur_n);
    bucket_sort<<<2 * NBUCK, 256, 0, stream>>>(buck_e, buck_n, gcur_e, gcur_n,
                                               csr_e, csr_n, off_e, off_n);

    // 3) GEMM1 (MFMA, LDS-staged, R5-verified)
    gemm1_mfma<<<NNODES / 32, 256, 0, stream>>>(x0, Wnh_bf, b_nh, A_bf);

    // 4) node -> hyperedge pull-aggregate (+ fused x1_out)
    seg_sum_fin_v2<8><<<(NEDGES + 3) / 4, 256, 0, stream>>>(
        A_bf, csr_e, off_e, x1, bn1g, bn1b, bn1m, bn1v, B, out1, NEDGES);

    // 5) GEMM2 register-MFMA (split-bf16, no LDS, R8/R9-verified)
    gemm2_reg<<<(NEDGES / 32) * 2, 256, 0, stream>>>(
        x1, B, W1hi, W1lo, W2hi, W2lo, b_en, D_bf);

    // 6) hyperedge -> node pull-aggregate (+ fused x0_out)
    seg_sum_fin_v2<4><<<(NNODES + 3) / 4, 256, 0, stream>>>(
        D_bf, csr_n, off_n, x0, bn0g, bn0b, bn0m, bn0v, nullptr, out0, NNODES);
}

// Round 11
// 390.544 us; speedup vs baseline: 1.0243x; 1.0036x over previous
//
#include <hip/hip_runtime.h>
#include <hip/hip_bf16.h>
#include <math.h>

#define NNODES 100000
#define NEDGES 20000
#define NNZ_   2000000
#define FDIM   128
#define BN_EPS 1e-5f

// ---- bucket-sort geometry (R1/R5 verified) ----
#define NBUCK 256
#define CAP   9216        // per-bucket capacity (mean ~7812, sigma ~88 -> +16 sigma)
#define BPB_E 79          // bins/bucket, edge dir
#define BPB_N 391         // bins/bucket, node dir
#define SH_E  17          // edge entry = (e<<17)|n
#define SH_N  15          // node entry = (n<<15)|e

typedef __attribute__((ext_vector_type(8))) short bf16x8_t;
typedef __attribute__((ext_vector_type(4))) float f32x4_t;
typedef __attribute__((ext_vector_type(8))) unsigned short u16x8_t;

__device__ __forceinline__ float sigmoidf_(float x) {
    return 1.0f / (1.0f + __expf(-x));
}
__device__ __forceinline__ float bf2f(unsigned short u) {
    return __uint_as_float(((unsigned)u) << 16);
}
__device__ __forceinline__ unsigned short f2bf(float f) {
    __hip_bfloat16 h = __float2bfloat16(f);   // RNE
    return *reinterpret_cast<unsigned short*>(&h);
}

// ---- prep (FIRST dispatch): zero gcur + bf16 W_nh + hi/lo split W_en ----
__global__ __launch_bounds__(256) void prep_w(
    const float* __restrict__ W_nh, const float* __restrict__ W_en,
    unsigned short* __restrict__ Wnh_bf,
    unsigned short* __restrict__ W1hi, unsigned short* __restrict__ W1lo,
    unsigned short* __restrict__ W2hi, unsigned short* __restrict__ W2lo,
    int* __restrict__ gcur)
{
    int idx = blockIdx.x * blockDim.x + threadIdx.x;
    if (idx < 2 * NBUCK) gcur[idx] = 0;
    if (idx < FDIM * FDIM) {
        Wnh_bf[idx] = f2bf(W_nh[idx]);
        return;
    }
    int j = idx - FDIM * FDIM;
    if (j >= 2 * FDIM * FDIM) return;
    int n = j >> 8, kk = j & 255;
    float w = W_en[n * 2 * FDIM + kk];
    unsigned short hi = f2bf(w);
    unsigned short lo = f2bf(w - bf2f(hi));
    int o = n * FDIM + (kk & 127);
    if (kk < FDIM) { W1hi[o] = hi; W1lo[o] = lo; }
    else           { W2hi[o] = hi; W2lo[o] = lo; }
}

// ---- GEMM1 via MFMA (R5-verified LDS version) ----
__global__ __launch_bounds__(256) void gemm1_mfma(
    const float* __restrict__ x0, const unsigned short* __restrict__ Wb,
    const float* __restrict__ bias, unsigned short* __restrict__ out)
{
    __shared__ unsigned short As[32][FDIM + 8];
    const int tid  = threadIdx.x;
    const int row0 = blockIdx.x * 32;
    {
        int r = tid >> 3, c0 = (tid & 7) * 16;
        const float* src = x0 + (size_t)(row0 + r) * FDIM + c0;
        unsigned short* dst = &As[r][c0];
        #pragma unroll
        for (int i = 0; i < 4; i++) {
            float4 v = *(const float4*)(src + i * 4);
            dst[i * 4 + 0] = f2bf(v.x);
            dst[i * 4 + 1] = f2bf(v.y);
            dst[i * 4 + 2] = f2bf(v.z);
            dst[i * 4 + 3] = f2bf(v.w);
        }
    }
    __syncthreads();
    const int wave  = tid >> 6;
    const int lane  = tid & 63;
    const int mhalf = wave & 1;
    const int nhalf = wave >> 1;
    const int lm    = lane & 15;
    const int quad  = lane >> 4;
    f32x4_t acc[4] = {};
    #pragma unroll
    for (int ks = 0; ks < 4; ks++) {
        bf16x8_t a = *(const bf16x8_t*)&As[mhalf * 16 + lm][ks * 32 + quad * 8];
        #pragma unroll
        for (int nt = 0; nt < 4; nt++) {
            int n = nhalf * 64 + nt * 16 + lm;
            bf16x8_t b = *(const bf16x8_t*)(Wb + (size_t)n * FDIM + ks * 32 + quad * 8);
            acc[nt] = __builtin_amdgcn_mfma_f32_16x16x32_bf16(a, b, acc[nt], 0, 0, 0);
        }
    }
    const int mbase = row0 + mhalf * 16 + quad * 4;
    #pragma unroll
    for (int nt = 0; nt < 4; nt++) {
        int n = nhalf * 64 + nt * 16 + lm;
        float bv = bias[n];
        #pragma unroll
        for (int r2 = 0; r2 < 4; r2++) {
            out[(size_t)(mbase + r2) * FDIM + n] = f2bf(sigmoidf_(acc[nt][r2] + bv));
        }
    }
}

// ---- GEMM2 via MFMA + bf16 error-compensated splitting (R5-verified) ----
// D = sigmoid(x1@W1^T + B@W2^T + b); each product via 3-pass hi/lo split.
__global__ __launch_bounds__(256) void gemm2_mfma(
    const float* __restrict__ x1, const float* __restrict__ Bagg,
    const unsigned short* __restrict__ W1hi, const unsigned short* __restrict__ W1lo,
    const unsigned short* __restrict__ W2hi, const unsigned short* __restrict__ W2lo,
    const float* __restrict__ bias, unsigned short* __restrict__ out)
{
    __shared__ unsigned short Ax[2][32][FDIM + 8];   // x1 hi, lo
    __shared__ unsigned short Ab[2][32][FDIM + 8];   // B  hi, lo
    const int tid  = threadIdx.x;
    const int row0 = blockIdx.x * 32;
    {
        int r = tid >> 3, c0 = (tid & 7) * 16;
        const float* sx = x1   + (size_t)(row0 + r) * FDIM + c0;
        const float* sb = Bagg + (size_t)(row0 + r) * FDIM + c0;
        #pragma unroll
        for (int i = 0; i < 4; i++) {
            float4 v = *(const float4*)(sx + i * 4);
            float4 w = *(const float4*)(sb + i * 4);
            #pragma unroll
            for (int c = 0; c < 4; c++) {
                float fv = (c == 0) ? v.x : (c == 1) ? v.y : (c == 2) ? v.z : v.w;
                unsigned short h = f2bf(fv);
                Ax[0][r][c0 + i * 4 + c] = h;
                Ax[1][r][c0 + i * 4 + c] = f2bf(fv - bf2f(h));
                float fw = (c == 0) ? w.x : (c == 1) ? w.y : (c == 2) ? w.z : w.w;
                unsigned short hb = f2bf(fw);
                Ab[0][r][c0 + i * 4 + c] = hb;
                Ab[1][r][c0 + i * 4 + c] = f2bf(fw - bf2f(hb));
            }
        }
    }
    __syncthreads();
    const int wave  = tid >> 6;
    const int lane  = tid & 63;
    const int mhalf = wave & 1;
    const int nhalf = wave >> 1;
    const int lm    = lane & 15;
    const int quad  = lane >> 4;
    f32x4_t acc[4] = {};
    const unsigned short* Wsel[6] = {W1hi, W1hi, W1lo, W2hi, W2hi, W2lo};
    #pragma unroll
    for (int ps = 0; ps < 6; ps++) {
        const unsigned short (*Asel)[FDIM + 8] =
            (ps < 3) ? ((ps == 1) ? Ax[1] : Ax[0])
                     : ((ps == 4) ? Ab[1] : Ab[0]);
        const unsigned short* Wp = Wsel[ps];
        #pragma unroll
        for (int ks = 0; ks < 4; ks++) {
            bf16x8_t a = *(const bf16x8_t*)&Asel[mhalf * 16 + lm][ks * 32 + quad * 8];
            #pragma unroll
            for (int nt = 0; nt < 4; nt++) {
                int n = nhalf * 64 + nt * 16 + lm;
                bf16x8_t b = *(const bf16x8_t*)(Wp + (size_t)n * FDIM + ks * 32 + quad * 8);
                acc[nt] = __builtin_amdgcn_mfma_f32_16x16x32_bf16(a, b, acc[nt], 0, 0, 0);
            }
        }
    }
    const int mbase = row0 + mhalf * 16 + quad * 4;
    #pragma unroll
    for (int nt = 0; nt < 4; nt++) {
        int n = nhalf * 64 + nt * 16 + lm;
        float bv = bias[n];
        #pragma unroll
        for (int r2 = 0; r2 < 4; r2++) {
            out[(size_t)(mbase + r2) * FDIM + n] = f2bf(sigmoidf_(acc[nt][r2] + bv));
        }
    }
}

// ---- Pass A: coarse bucket partition (R5 verified) ----
__global__ __launch_bounds__(1024) void bucket_scatter(
    const int* __restrict__ ni, const int* __restrict__ ei,
    unsigned* __restrict__ buck_e, unsigned* __restrict__ buck_n,
    int* __restrict__ gcur_e, int* __restrict__ gcur_n)
{
    __shared__ int lh_e[NBUCK], lh_n[NBUCK], lb_e[NBUCK], lb_n[NBUCK];
    const int t = threadIdx.x;
    if (t < NBUCK) { lh_e[t] = 0; lh_n[t] = 0; }
    __syncthreads();
    unsigned ent_e[4], ent_n[4];
    int be[4], bn[4], re[4], rn[4];
    const int base = blockIdx.x * 4096;
    #pragma unroll
    for (int j = 0; j < 4; j++) {
        int i = base + j * 1024 + t;
        if (i < NNZ_) {
            unsigned n = (unsigned)ni[i], e = (unsigned)ei[i];
            ent_e[j] = (e << SH_E) | n;  be[j] = (int)(e / BPB_E);
            ent_n[j] = (n << SH_N) | e;  bn[j] = (int)(n / BPB_N);
            re[j] = atomicAdd(&lh_e[be[j]], 1);
            rn[j] = atomicAdd(&lh_n[bn[j]], 1);
        } else { be[j] = -1; }
    }
    __syncthreads();
    if (t < NBUCK) {
        lb_e[t] = t * CAP + atomicAdd(&gcur_e[t], lh_e[t]);
        lb_n[t] = t * CAP + atomicAdd(&gcur_n[t], lh_n[t]);
    }
    __syncthreads();
    #pragma unroll
    for (int j = 0; j < 4; j++) {
        if (be[j] >= 0) {
            buck_e[(size_t)lb_e[be[j]] + re[j]] = ent_e[j];
            buck_n[(size_t)lb_n[bn[j]] + rn[j]] = ent_n[j];
        }
    }
}

// ---- Pass B: sort one bucket; csr stores PREMULTIPLIED (idx<<7) offsets ----
template<int BPB, int SH, unsigned MASK, int NBINS>
__device__ __forceinline__ void sort_bucket(
    const unsigned* __restrict__ region, int cnt, int gbase, int b0,
    unsigned* __restrict__ csr, int* __restrict__ off)
{
    __shared__ unsigned lh[512];
    __shared__ unsigned lw[4];
    const int t = threadIdx.x;
    lh[t] = 0; lh[t + 256] = 0;
    __syncthreads();
    for (int i = t; i < cnt; i += 256) {
        int bin = (int)(region[i] >> SH) - b0;
        atomicAdd(&lh[bin], 1u);
    }
    __syncthreads();
    unsigned h0 = lh[2 * t], h1 = lh[2 * t + 1];
    unsigned s = h0 + h1, inc = s;
    const int lane = t & 63;
    #pragma unroll
    for (int d = 1; d <= 32; d <<= 1) {
        unsigned v = (unsigned)__shfl_up((int)inc, d, 64);
        if (lane >= d) inc += v;
    }
    if (lane == 63) lw[t >> 6] = inc;
    __syncthreads();
    unsigned pre = 0;
    #pragma unroll
    for (int w = 0; w < 4; w++) if (w < (t >> 6)) pre += lw[w];
    unsigned excl = pre + inc - s;
    unsigned c0 = (unsigned)gbase + excl;
    unsigned c1 = c0 + h0;
    lh[2 * t] = c0; lh[2 * t + 1] = c1;
    int i0 = 2 * t, i1 = 2 * t + 1;
    if (i0 <= BPB && b0 + i0 <= NBINS) off[b0 + i0] = (int)c0;
    if (i1 <= BPB && b0 + i1 <= NBINS) off[b0 + i1] = (int)c1;
    __syncthreads();
    for (int i = t; i < cnt; i += 256) {
        unsigned ent = region[i];
        int bin = (int)(ent >> SH) - b0;
        unsigned pos = atomicAdd(&lh[bin], 1u);
        csr[pos] = (ent & MASK) << 7;   // element offset = idx * FDIM
    }
}

__global__ __launch_bounds__(256) void bucket_sort(
    const unsigned* __restrict__ buck_e, const unsigned* __restrict__ buck_n,
    const int* __restrict__ gcur_e, const int* __restrict__ gcur_n,
    unsigned* __restrict__ csr_e, unsigned* __restrict__ csr_n,
    int* __restrict__ off_e, int* __restrict__ off_n)
{
    const int b = blockIdx.x & 255;
    const int* gc = (blockIdx.x < 256) ? gcur_e : gcur_n;
    __shared__ int ws4[4];
    const int t = threadIdx.x;
    int v = (t < b) ? gc[t] : 0;
    #pragma unroll
    for (int d = 32; d > 0; d >>= 1) v += __shfl_down(v, d, 64);
    if ((t & 63) == 0) ws4[t >> 6] = v;
    __syncthreads();
    const int gbase = ws4[0] + ws4[1] + ws4[2] + ws4[3];
    const int cnt = gc[b];
    __syncthreads();
    if (blockIdx.x < 256)
        sort_bucket<BPB_E, SH_E, 0x1FFFFu, NEDGES>(
            buck_e + (size_t)b * CAP, cnt, gbase, b * BPB_E, csr_e, off_e);
    else
        sort_bucket<BPB_N, SH_N, 0x7FFFu, NNODES>(
            buck_n + (size_t)b * CAP, cnt, gbase, b * BPB_N, csr_n, off_n);
}

// ---- segmented sum v2: one wave/segment; csr holds premultiplied offsets ----
template<int U>
__global__ __launch_bounds__(256) void seg_sum_fin_v2(
    const unsigned short* __restrict__ table, const unsigned* __restrict__ csr,
    const int* __restrict__ off, const float* __restrict__ x,
    const float* __restrict__ g, const float* __restrict__ bb,
    const float* __restrict__ mm, const float* __restrict__ vv,
    float* __restrict__ agg_out, float* __restrict__ fin_out, int nseg)
{
    const int seg = blockIdx.x * 4 + (threadIdx.x >> 6);
    if (seg >= nseg) return;
    const int lane = threadIdx.x & 63;
    const int c    = lane & 15;
    const int sub  = lane >> 4;
    const int c8   = c * 8;

    const int i0 = off[seg], i1 = off[seg + 1];
    f32x4_t a0 = {}, a1 = {};

    int i = i0;
    for (; i + 4 * U <= i1; i += 4 * U) {
        unsigned r[U];
        u16x8_t v[U];
        #pragma unroll
        for (int u = 0; u < U; u++) r[u] = csr[i + 4 * u + sub];
        #pragma unroll
        for (int u = 0; u < U; u++)
            v[u] = *(const u16x8_t*)(table + (size_t)r[u] + c8);
        #pragma unroll
        for (int u = 0; u < U; u++) {
            a0[0] += bf2f(v[u][0]); a0[1] += bf2f(v[u][1]);
            a0[2] += bf2f(v[u][2]); a0[3] += bf2f(v[u][3]);
            a1[0] += bf2f(v[u][4]); a1[1] += bf2f(v[u][5]);
            a1[2] += bf2f(v[u][6]); a1[3] += bf2f(v[u][7]);
        }
    }
    if (i < i1) {
        u16x8_t v[U];
        #pragma unroll
        for (int u = 0; u < U; u++) {
            int row = i + 4 * u + sub;
            u16x8_t z = {};
            v[u] = z;
            if (row < i1)
                v[u] = *(const u16x8_t*)(table + (size_t)csr[row] + c8);
        }
        #pragma unroll
        for (int u = 0; u < U; u++) {
            a0[0] += bf2f(v[u][0]); a0[1] += bf2f(v[u][1]);
            a0[2] += bf2f(v[u][2]); a0[3] += bf2f(v[u][3]);
            a1[0] += bf2f(v[u][4]); a1[1] += bf2f(v[u][5]);
            a1[2] += bf2f(v[u][6]); a1[3] += bf2f(v[u][7]);
        }
    }

    #pragma unroll
    for (int j = 0; j < 4; j++) {
        a0[j] += __shfl_xor(a0[j], 16, 64);
        a0[j] += __shfl_xor(a0[j], 32, 64);
        a1[j] += __shfl_xor(a1[j], 16, 64);
        a1[j] += __shfl_xor(a1[j], 32, 64);
    }

    if (sub < 2) {
        const int q = c8 + sub * 4;
        f32x4_t s = sub ? a1 : a0;
        if (agg_out)
            *(f32x4_t*)(agg_out + (size_t)seg * FDIM + q) = s;
        if (fin_out) {
            f32x4_t xv = *(const f32x4_t*)(x + (size_t)seg * FDIM + q);
            f32x4_t gg = *(const f32x4_t*)(g + q);
            f32x4_t bt = *(const f32x4_t*)(bb + q);
            f32x4_t mn = *(const f32x4_t*)(mm + q);
            f32x4_t vr = *(const f32x4_t*)(vv + q);
            f32x4_t o;
            #pragma unroll
            for (int j = 0; j < 4; j++)
                o[j] = sigmoidf_((xv[j] - mn[j]) * (gg[j] * rsqrtf(vr[j] + BN_EPS))
                                 + bt[j] + s[j]);
            *(f32x4_t*)(fin_out + (size_t)seg * FDIM + q) = o;
        }
    }
}

extern "C" void kernel_launch(void* const* d_in, const int* in_sizes, int n_in,
                              void* d_out, int out_size, void* d_ws, size_t ws_size,
                              hipStream_t stream)
{
    const float* x0       = (const float*)d_in[0];
    const float* x1       = (const float*)d_in[1];
    const int*   node_idx = (const int*)d_in[2];
    const int*   edge_idx = (const int*)d_in[3];
    const float* W_nh     = (const float*)d_in[4];
    const float* b_nh     = (const float*)d_in[5];
    const float* W_en     = (const float*)d_in[6];
    const float* b_en     = (const float*)d_in[7];
    const float* bn0g = (const float*)d_in[8];
    const float* bn0b = (const float*)d_in[9];
    const float* bn0m = (const float*)d_in[10];
    const float* bn0v = (const float*)d_in[11];
    const float* bn1g = (const float*)d_in[12];
    const float* bn1b = (const float*)d_in[13];
    const float* bn1m = (const float*)d_in[14];
    const float* bn1v = (const float*)d_in[15];

    float* ws = (float*)d_ws;
    float* B = ws;                                        // [20000,128] fp32
    unsigned short* Wnh_bf = (unsigned short*)(B + (size_t)NEDGES * FDIM);
    unsigned short* W1hi = Wnh_bf + FDIM * FDIM;
    unsigned short* W1lo = W1hi + FDIM * FDIM;
    unsigned short* W2hi = W1lo + FDIM * FDIM;
    unsigned short* W2lo = W2hi + FDIM * FDIM;
    unsigned short* A_bf = W2lo + FDIM * FDIM;            // [100000,128] bf16
    unsigned short* D_bf = A_bf + (size_t)NNODES * FDIM;  // [20000,128] bf16
    int* off_e = (int*)(D_bf + (size_t)NEDGES * FDIM);    // 20001 (pad 20004)
    int* off_n = off_e + 20004;                           // 100001 (pad 100004)
    unsigned* csr_e = (unsigned*)(off_n + 100004);        // 2M u32 (premul offsets)
    unsigned* csr_n = csr_e + NNZ_;                       // 2M u32 (premul offsets)
    unsigned* buck_e = csr_n + NNZ_;                      // [NBUCK*CAP]
    unsigned* buck_n = buck_e + (size_t)NBUCK * CAP;      // [NBUCK*CAP]
    int* gcur_e = (int*)(buck_n + (size_t)NBUCK * CAP);   // 256
    int* gcur_n = gcur_e + NBUCK;                         // 256

    // 1) prep: zero gcur + weight conversions/splits
    prep_w<<<(3 * FDIM * FDIM + 255) / 256, 256, 0, stream>>>(
        W_nh, W_en, Wnh_bf, W1hi, W1lo, W2hi, W2lo, gcur_e);

    float* out0 = (float*)d_out;
    float* out1 = out0 + (size_t)NNODES * FDIM;

    // 2) CSR build: scatter then sort (premultiplied csr offsets)
    bucket_scatter<<<(NNZ_ + 4095) / 4096, 1024, 0, stream>>>(
        node_idx, edge_idx, buck_e, buck_n, gcur_e, gcur_n);
    bucket_sort<<<2 * NBUCK, 256, 0, stream>>>(buck_e, buck_n, gcur_e, gcur_n,
                                               csr_e, csr_n, off_e, off_n);

    // 3) GEMM1 (MFMA, LDS-staged, R5-verified)
    gemm1_mfma<<<NNODES / 32, 256, 0, stream>>>(x0, Wnh_bf, b_nh, A_bf);

    // 4) node -> hyperedge pull-aggregate (+ fused x1_out)
    seg_sum_fin_v2<8><<<(NEDGES + 3) / 4, 256, 0, stream>>>(
        A_bf, csr_e, off_e, x1, bn1g, bn1b, bn1m, bn1v, B, out1, NEDGES);

    // 5) GEMM2 (MFMA, split-bf16 LDS version, R5-verified)
    gemm2_mfma<<<NEDGES / 32, 256, 0, stream>>>(
        x1, B, W1hi, W1lo, W2hi, W2lo, b_en, D_bf);

    // 6) hyperedge -> node pull-aggregate (+ fused x0_out)
    seg_sum_fin_v2<4><<<(NNODES + 3) / 4, 256, 0, stream>>>(
        D_bf, csr_n, off_n, x0, bn0g, bn0b, bn0m, bn0v, nullptr, out0, NNODES);
}